// Round 8
// baseline (555.302 us; speedup 1.0000x reference)
//
#include <hip/hip_runtime.h>
#include <math.h>

#define NROWS 8192
#define DIM   256
#define NCLS  64
#define KNN   5
#define NCAND 8      // per (row, j-split)
#define NSPLIT 4
#define MAXSTEPS 100
#define PBLK 256     // persistent-solver blocks: 1 per CU -> co-residency guaranteed

struct GS {
  double Eold;
  double Epart[PBLK];
  double Egrp[8];
  int gcnt[8 * 32];   // per-group arrival counters, 128B-spaced
  int gen[8 * 32];    // 8 generation mirrors, 128B-spaced
  int gcount;         // group-finalizer count
  int flag;
};

typedef __attribute__((ext_vector_type(8))) short bf16x8;
typedef __attribute__((ext_vector_type(4))) float f32x4;

typedef __attribute__((address_space(1))) unsigned int glb_u32_t;
typedef __attribute__((address_space(3))) unsigned int lds_u32_t;
// async global->LDS DMA, 16 B/lane; LDS dest = wave-uniform base + lane*16
__device__ __forceinline__ void async_cp16(const uint4* g, uint4* l) {
  __builtin_amdgcn_global_load_lds((const glb_u32_t*)(const unsigned int*)g,
                                   (lds_u32_t*)(unsigned int*)l, 16, 0, 0);
}

// ---------------- wave (64-lane) reductions ----------------
__device__ __forceinline__ float wave_sum64(float v) {
#pragma unroll
  for (int m = 32; m >= 1; m >>= 1) v += __shfl_xor(v, m, 64);
  return v;
}
__device__ __forceinline__ double wave_sum64d(double v) {
#pragma unroll
  for (int m = 32; m >= 1; m >>= 1) v += __shfl_xor(v, m, 64);
  return v;
}

__device__ __forceinline__ unsigned short f2bf(float x) {  // RNE bf16
  unsigned u = __float_as_uint(x);
  u += 0x7FFFu + ((u >> 16) & 1u);
  return (unsigned short)(u >> 16);
}

// ---------------- 1. normalize: bf16 swizzled tiles + fp32 f + sqd ----------------
// fb layout (uint4 granules = 8 bf16 dims): row r -> tile T=r>>6, local row
// rl=r&63, granule g: fb_uint4[T*2048 + rl*32 + (g ^ (rl&31))].
// f = fl(feats/nrm) fp32 linear (refine reads it; region is reused as Ya/Yb).
__global__ void k_normalize(const float* __restrict__ feats, uint2* __restrict__ fb2,
                            float* __restrict__ f, double* __restrict__ sqd) {
  int row  = blockIdx.x * 4 + (threadIdx.x >> 6);
  int lane = threadIdx.x & 63;
  float4 v = ((const float4*)(feats + (size_t)row * DIM))[lane];
  double ss = (double)v.x * v.x + (double)v.y * v.y + (double)v.z * v.z + (double)v.w * v.w;
  ss = wave_sum64d(ss);
  float nr = fmaxf((float)sqrt(ss), 1e-12f);
  float4 o;  // exact fp32 division
  o.x = v.x / nr; o.y = v.y / nr; o.z = v.z / nr; o.w = v.w / nr;
  ((float4*)(f + (size_t)row * DIM))[lane] = o;
  double s2 = (double)o.x * o.x + (double)o.y * o.y + (double)o.z * o.z + (double)o.w * o.w;
  s2 = wave_sum64d(s2);
  if (lane == 0) sqd[row] = s2;
  uint2 w2;
  w2.x = (unsigned)f2bf(o.x) | ((unsigned)f2bf(o.y) << 16);
  w2.y = (unsigned)f2bf(o.z) | ((unsigned)f2bf(o.w) << 16);
  int T = row >> 6, rl = row & 63, g = lane >> 1, h = lane & 1;
  fb2[((size_t)T * 2048 + rl * 32 + (g ^ (rl & 31))) * 2 + h] = w2;
}

// ---------------- 2. MFMA bf16 candidate Gram + per-row top-8 ----------------
// grid 512: (row-block ib 0..127) x (j-split js 0..3). A-fragments in regs;
// double-buffered B via async DMA -> one barrier per tile. Wave-local branchy
// top-k; per-tile partner-shuffle tightens thr to the 2-segment-union 8th
// best (safe: a value below another segment's 8th best cannot be in the
// merged union top-8).
#define JSPAN (NROWS / NSPLIT)  // 2048
#define GTILES (JSPAN / 64)     // 32

__launch_bounds__(256, 2)
__global__ void k_gram(const uint4* __restrict__ fb, int* __restrict__ candp) {
  __shared__ uint4 Bsh4[2][2048];   // 64 KB; buf1 stages A first
  __shared__ float Csh[4096];       // 16 KB: per-wave C quadrants / merge

  const int t  = threadIdx.x;
  const int ib = blockIdx.x >> 2;
  const int js = blockIdx.x & 3;
  const int i0 = ib * 64;
  const int jbase = js * JSPAN;
  const int w = t >> 6, lane = t & 63;

  // DMA: A -> buf1, B tile0 -> buf0
  {
    const uint4* At = fb + (size_t)ib * 2048;
    const uint4* Bt = fb + (size_t)(js * 32) * 2048;
#pragma unroll
    for (int p = 0; p < 8; ++p) {
      int c = w * 8 + p;
      async_cp16(At + c * 64 + lane, &Bsh4[1][c * 64]);
      async_cp16(Bt + c * 64 + lane, &Bsh4[0][c * 64]);
    }
  }
  const int ihalf = w >> 1, jhalf = w & 1;
  const int m15 = lane & 15, quad = lane >> 4;

  __syncthreads();  // drain DMA: A + B0 visible

  // A-quadrant fragments -> registers
  bf16x8 areg[2][8];
#pragma unroll
  for (int s = 0; s < 2; ++s) {
    int ra = ihalf * 32 + s * 16 + m15;
#pragma unroll
    for (int kc = 0; kc < 8; ++kc)
      areg[s][kc] = ((const bf16x8*)Bsh4[1])[ra * 32 + ((kc * 4 + quad) ^ (ra & 31))];
  }
  __syncthreads();  // buf1 reusable

  unsigned mk[NCAND];
#pragma unroll
  for (int k = 0; k < NCAND; ++k) mk[k] = 0u;
  float thr = -1e30f;

  const int trow = lane >> 1;   // local row 0..31 of wave quadrant
  const int thalf = lane & 1;   // 16-col half
  float* Csw = Csh + w * 1024;

  for (int jt = 0; jt < GTILES; ++jt) {
    const int cbuf = jt & 1;
    if (jt > 0) __syncthreads();
    if (jt + 1 < GTILES) {
      const uint4* Bt = fb + (size_t)(js * 32 + jt + 1) * 2048;
#pragma unroll
      for (int p = 0; p < 8; ++p) {
        int c = w * 8 + p;
        async_cp16(Bt + c * 64 + lane, &Bsh4[1 - cbuf][c * 64]);
      }
    }

    f32x4 acc[2][2];
#pragma unroll
    for (int si = 0; si < 2; ++si)
#pragma unroll
      for (int sj = 0; sj < 2; ++sj) acc[si][sj] = (f32x4)(0.f);

#pragma unroll
    for (int kc = 0; kc < 8; ++kc) {
      bf16x8 bv[2];
#pragma unroll
      for (int s = 0; s < 2; ++s) {
        int rb = jhalf * 32 + s * 16 + m15;
        bv[s] = ((const bf16x8*)Bsh4[cbuf])[rb * 32 + ((kc * 4 + quad) ^ (rb & 31))];
      }
      acc[0][0] = __builtin_amdgcn_mfma_f32_16x16x32_bf16(areg[0][kc], bv[0], acc[0][0], 0, 0, 0);
      acc[0][1] = __builtin_amdgcn_mfma_f32_16x16x32_bf16(areg[0][kc], bv[1], acc[0][1], 0, 0, 0);
      acc[1][0] = __builtin_amdgcn_mfma_f32_16x16x32_bf16(areg[1][kc], bv[0], acc[1][0], 0, 0, 0);
      acc[1][1] = __builtin_amdgcn_mfma_f32_16x16x32_bf16(areg[1][kc], bv[1], acc[1][1], 0, 0, 0);
    }

    // C scatter -> wave-local quadrant (32x32); swizzle key quad*2 pairs the
    // 4 stores of each acc float4 (+0/+128/+256/+384 B).
#pragma unroll
    for (int si = 0; si < 2; ++si)
#pragma unroll
      for (int sj = 0; sj < 2; ++sj) {
        int lr0 = si * 16 + quad * 4;
        int key = quad * 2;
        int lc = sj * 16 + m15;
        int gc = lc >> 2;
        int base = lr0 * 32 + ((gc ^ key) << 2) + (lc & 3);
#pragma unroll
        for (int r = 0; r < 4; ++r)
          Csw[base + r * 32] = acc[si][sj][r];
      }

    // wave-local top-8: lane scans (row trow, cols thalf*16..+15)
    {
      int cb0 = jt * 64 + jhalf * 32;
      int skey = (trow >> 1) & 6;
#pragma unroll
      for (int p = 0; p < 4; ++p) {
        int gc = thalf * 4 + p;
        float4 v = *(const float4*)&Csw[trow * 32 + ((gc ^ skey) << 2)];
        float g4 = fmaxf(fmaxf(v.x, v.y), fmaxf(v.z, v.w));
        if (g4 > thr) {
          int cbase = cb0 + gc * 4;
          float vv[4] = {v.x, v.y, v.z, v.w};
#pragma unroll
          for (int e = 0; e < 4; ++e) {
            unsigned ub = __float_as_uint(vv[e]);
            unsigned key = ((ub ^ (unsigned)(((int)ub >> 31) | 0x80000000)) & ~2047u)
                           | (unsigned)(cbase + e);
            if (key > mk[NCAND - 1]) {
              mk[NCAND - 1] = key;
#pragma unroll
              for (int q = NCAND - 1; q >= 1; --q)
                if (mk[q] > mk[q - 1]) { unsigned tm = mk[q]; mk[q] = mk[q - 1]; mk[q - 1] = tm; }
            }
          }
        }
      }
    }
    // tighten thr with partner segment (same row, other 16-col half): the
    // pair-union 8th best is a valid drop threshold for both segments.
    {
      unsigned pk = mk[NCAND - 1] & ~2047u;
      unsigned qk = (unsigned)__shfl_xor((int)mk[NCAND - 1], 1, 64) & ~2047u;
      unsigned bk = pk > qk ? pk : qk;
      if (bk) {
        unsigned xm = 0x80000000u | ~(unsigned)((int)bk >> 31);
        thr = __uint_as_float(bk ^ xm);
      }
    }
  }

  // ---- merge 4 per-thread lists per row -> top-8 per (row, split) ----
  __syncthreads();
  unsigned* mergeK = (unsigned*)Csh;  // [64][33]
  {
    int grow = ihalf * 32 + trow;
    int q = jhalf * 2 + thalf;
#pragma unroll
    for (int k = 0; k < NCAND; ++k) mergeK[grow * 33 + q * 8 + k] = mk[k];
  }
  __syncthreads();
  if (t < 64) {
    unsigned fk[NCAND];
#pragma unroll
    for (int k = 0; k < NCAND; ++k) fk[k] = 0u;
    for (int s = 0; s < 32; ++s) {
      unsigned kk = mergeK[t * 33 + s];
      if (kk > fk[NCAND - 1]) {
        fk[NCAND - 1] = kk;
#pragma unroll
        for (int q = NCAND - 1; q >= 1; --q)
          if (fk[q] > fk[q - 1]) { unsigned tm = fk[q]; fk[q] = fk[q - 1]; fk[q - 1] = tm; }
      }
    }
#pragma unroll
    for (int k = 0; k < NCAND; ++k)
      candp[(size_t)js * (NROWS * NCAND) + (size_t)(i0 + t) * NCAND + k] =
          jbase + (int)(fk[k] & 2047u);
  }
}

// ---------------- 3. fp64 exact refine (no divides: reads stored f) ----------------
__global__ void k_refine(const float* __restrict__ f, const double* __restrict__ sqd,
                         const int* __restrict__ candp, int* __restrict__ nbr) {
  const int row = blockIdx.x * 4 + (threadIdx.x >> 6);
  const int t = threadIdx.x & 63;
  const int c = t >> 1;        // candidate 0..31
  const int seg = t & 1;       // half of D
  const int split = c >> 3, slot = c & 7;
  int j = candp[(size_t)split * (NROWS * NCAND) + (size_t)row * NCAND + slot];
  const float4* fi4 = (const float4*)(f + (size_t)row * DIM) + seg * 32;
  const float4* fj4 = (const float4*)(f + (size_t)j * DIM) + seg * 32;
  double dot = 0.0;
#pragma unroll 8
  for (int d4 = 0; d4 < 32; ++d4) {
    float4 a = fi4[d4], b = fj4[d4];
    dot = fma((double)a.x, (double)b.x, dot);
    dot = fma((double)a.y, (double)b.y, dot);
    dot = fma((double)a.z, (double)b.z, dot);
    dot = fma((double)a.w, (double)b.w, dot);
  }
  dot += __shfl_xor(dot, 1, 64);
  double key = sqd[j] - 2.0 * dot;
  bool valid = (seg == 0) && (j != row);
  for (int s = 0; s < KNN; ++s) {
    double v = valid ? key : (double)INFINITY;
    int vj = valid ? j : 0x7fffffff;
#pragma unroll
    for (int m = 1; m < 64; m <<= 1) {
      double ov = __shfl_xor(v, m, 64);
      int oj = __shfl_xor(vj, m, 64);
      if (ov < v || (ov == v && oj < vj)) { v = ov; vj = oj; }
    }
    if (valid && vj == j) valid = false;
    if (t == 0) nbr[(size_t)row * 8 + s] = vj;
  }
}

// ---------------- 2-level grid barrier (thread 0 of each block) ----------------
__device__ __forceinline__ int grid_barrier(GS* gs, int b, int mygen, int iter,
                                            double blockE, bool doE) {
  const int g = b >> 5;
  if (doE) gs->Epart[b] = blockE;
  __threadfence();
  int a = atomicAdd(&gs->gcnt[g * 32], 1);
  if (a == 31) {          // group finalizer
    __threadfence();
    if (doE) {
      double s = 0.0;
#pragma unroll
      for (int i = 0; i < 32; ++i) s += gs->Epart[g * 32 + i];
      gs->Egrp[g] = s;
      __threadfence();
    }
    int ga = atomicAdd(&gs->gcount, 1);
    if (ga == 7) {        // global finalizer
      __threadfence();
      if (doE) {
        double E = 0.0;
#pragma unroll
        for (int m = 0; m < 8; ++m) E += gs->Egrp[m];
        int conv = (iter > 1) && (fabs(E - gs->Eold) <= 1e-8 * fabs(gs->Eold));
        gs->flag = conv;
        if (!conv) gs->Eold = E;
      }
      gs->gcount = 0;
#pragma unroll
      for (int m = 0; m < 8; ++m) gs->gcnt[m * 32] = 0;
      __threadfence();
#pragma unroll
      for (int m = 0; m < 8; ++m)
        __hip_atomic_store(&gs->gen[m * 32], mygen, __ATOMIC_RELEASE,
                           __HIP_MEMORY_SCOPE_AGENT);
    }
  }
  while (__hip_atomic_load(&gs->gen[g * 32], __ATOMIC_ACQUIRE,
                           __HIP_MEMORY_SCOPE_AGENT) < mygen)
    __builtin_amdgcn_s_sleep(1);
  __threadfence();
  return gs->flag;
}

// ---------------- 4. persistent solver: Y0 + all iterations + out ----------------
// 256 blocks x 512 threads (8 waves, 4 rows/wave, lane=class). Neighbor
// element-offsets precomputed in VGPRs (hoisted out of the 100-iter loop).
// Softmax without max-sub (logits in [-23,5]). E = -sum lse (LAM=1).
__global__ void k_solve(const float* __restrict__ scores,
                        const int* __restrict__ nbr,
                        float* __restrict__ Ya, float* __restrict__ Yb,
                        float* __restrict__ out, GS* __restrict__ gs) {
  const int b = blockIdx.x;
  const int w = threadIdx.x >> 6, lane = threadIdx.x & 63;
  const int row0 = b * 32 + w * 4;
  __shared__ int nbl[32][5];
  __shared__ double sE[8];
  __shared__ int sflag;

  if (threadIdx.x < 160)
    nbl[threadIdx.x / 5][threadIdx.x % 5] =
        nbr[(size_t)(b * 32 + threadIdx.x / 5) * 8 + (threadIdx.x % 5)];

  float u[4], y[4];
#pragma unroll
  for (int r = 0; r < 4; ++r)
    u[r] = -logf(scores[(size_t)(row0 + r) * NCLS + lane] + 1e-10f);
#pragma unroll
  for (int r = 0; r < 4; ++r) {
    float e = expf(-u[r]);
    float sum = wave_sum64(e);
    y[r] = e / sum;
    Ya[(size_t)(row0 + r) * NCLS + lane] = y[r];
  }
  __syncthreads();  // nbl ready; own Y0 stores complete

  // hoist neighbor element-offsets into registers
  int nboff[4][KNN];
#pragma unroll
  for (int r = 0; r < 4; ++r)
#pragma unroll
    for (int k = 0; k < KNN; ++k)
      nboff[r][k] = nbl[w * 4 + r][k] * NCLS + lane;

  int mygen = 1;
  if (threadIdx.x == 0) (void)grid_barrier(gs, b, mygen, -1, 0.0, false);
  __syncthreads();
  ++mygen;

  for (int iter = 0; iter < MAXSTEPS; ++iter) {
    const float* __restrict__ Yin = (iter & 1) ? Yb : Ya;
    float* __restrict__ Yout = (iter & 1) ? Ya : Yb;
    double ew = 0.0;
#pragma unroll
    for (int r = 0; r < 4; ++r) {
      float pw = 0.f;
#pragma unroll
      for (int k = 0; k < KNN; ++k) pw += Yin[nboff[r][k]];
      float e = expf(pw - u[r]);
      float sum = wave_sum64(e);
      y[r] = e / sum;
      Yout[(size_t)(row0 + r) * NCLS + lane] = y[r];
      ew += -(double)logf(sum);
    }
    if (lane == 0) sE[w] = ew;
    __syncthreads();  // sE ready + all Y stores issued
    if (threadIdx.x == 0) {
      double blockE = ((sE[0] + sE[1]) + (sE[2] + sE[3])) +
                      ((sE[4] + sE[5]) + (sE[6] + sE[7]));
      sflag = grid_barrier(gs, b, mygen, iter, blockE, true);
    }
    __syncthreads();
    ++mygen;
    if (sflag) break;  // uniform across grid
  }

#pragma unroll
  for (int r = 0; r < 4; ++r)
    out[(size_t)(row0 + r) * NCLS + lane] = y[r];
}

// ---------------- 0. state init ----------------
__global__ void k_init(GS* gs) {
  int t = threadIdx.x;
  if (t == 0) { gs->Eold = (double)INFINITY; gs->gcount = 0; gs->flag = 0; }
  if (t < 8 * 32) { gs->gcnt[t] = 0; gs->gen[t] = 0; }
}

extern "C" void kernel_launch(void* const* d_in, const int* in_sizes, int n_in,
                              void* d_out, int out_size, void* d_ws, size_t ws_size,
                              hipStream_t stream) {
  (void)in_sizes; (void)n_in; (void)out_size; (void)ws_size;
  const float* scores = (const float*)d_in[0];
  const float* feats  = (const float*)d_in[1];
  float* out = (float*)d_out;
  char* ws = (char*)d_ws;
  // workspace layout (256B-aligned); total ~14.0 MB (proven budget >= 16.07 MB)
  uint4*  fb    = (uint4*)(ws + 0);          //  4 MB pre-swizzled bf16 tiles
  float*  f     = (float*)(ws + 4194304);    //  8 MB fp32 normalized (dies after refine)
  float*  Ya    = (float*)(ws + 4194304);    //  2 MB (aliases f; live from k_solve)
  float*  Yb    = (float*)(ws + 6291456);    //  2 MB (aliases f)
  double* sqd   = (double*)(ws + 12582912);  // 64 KB
  int*    candp = (int*)(ws + 12648448);     //  1 MB (4 splits x 8192 x 8)
  int*    nbr   = (int*)(ws + 13697024);     // 256 KB
  GS*     gs    = (GS*)(ws + 13959168);      // ~4.3 KB

  k_init<<<1, 256, 0, stream>>>(gs);
  k_normalize<<<NROWS / 4, 256, 0, stream>>>(feats, (uint2*)fb, f, sqd);
  k_gram<<<(NROWS / 64) * NSPLIT, 256, 0, stream>>>(fb, candp);
  k_refine<<<NROWS / 4, 256, 0, stream>>>(f, sqd, candp, nbr);
  k_solve<<<PBLK, 512, 0, stream>>>(scores, nbr, Ya, Yb, out, gs);
}

// Round 9
// 376.555 us; speedup vs baseline: 1.4747x; 1.4747x over previous
//
#include <hip/hip_runtime.h>
#include <math.h>

#define NROWS 8192
#define DIM   256
#define NCLS  64
#define KNN   5
#define NCAND 8      // per (row, j-split)
#define NSPLIT 4
#define MAXSTEPS 100
#define PBLK 256     // persistent-solver blocks: 1 per CU -> co-residency guaranteed

struct GS {          // R6/R7-proven flat-barrier state
  double Eold;
  double Epart[PBLK];
  int count; int gen; int flag; int _pad;
};

typedef __attribute__((ext_vector_type(8))) short bf16x8;
typedef __attribute__((ext_vector_type(4))) float f32x4;

typedef __attribute__((address_space(1))) unsigned int glb_u32_t;
typedef __attribute__((address_space(3))) unsigned int lds_u32_t;
// async global->LDS DMA, 16 B/lane; LDS dest = wave-uniform base + lane*16
__device__ __forceinline__ void async_cp16(const uint4* g, uint4* l) {
  __builtin_amdgcn_global_load_lds((const glb_u32_t*)(const unsigned int*)g,
                                   (lds_u32_t*)(unsigned int*)l, 16, 0, 0);
}

// ---------------- wave (64-lane) reductions ----------------
__device__ __forceinline__ float wave_sum64(float v) {
#pragma unroll
  for (int m = 32; m >= 1; m >>= 1) v += __shfl_xor(v, m, 64);
  return v;
}
__device__ __forceinline__ double wave_sum64d(double v) {
#pragma unroll
  for (int m = 32; m >= 1; m >>= 1) v += __shfl_xor(v, m, 64);
  return v;
}

__device__ __forceinline__ unsigned short f2bf(float x) {  // RNE bf16
  unsigned u = __float_as_uint(x);
  u += 0x7FFFu + ((u >> 16) & 1u);
  return (unsigned short)(u >> 16);
}

// ---------------- 1. normalize: bf16 swizzled tiles + fp32 f + sqd ----------------
// fb layout (uint4 granules = 8 bf16 dims): row r -> tile T=r>>6, local row
// rl=r&63, granule g: fb_uint4[T*2048 + rl*32 + (g ^ (rl&31))].
__global__ void k_normalize(const float* __restrict__ feats, uint2* __restrict__ fb2,
                            float* __restrict__ f, double* __restrict__ sqd) {
  int row  = blockIdx.x * 4 + (threadIdx.x >> 6);
  int lane = threadIdx.x & 63;
  float4 v = ((const float4*)(feats + (size_t)row * DIM))[lane];
  double ss = (double)v.x * v.x + (double)v.y * v.y + (double)v.z * v.z + (double)v.w * v.w;
  ss = wave_sum64d(ss);
  float nr = fmaxf((float)sqrt(ss), 1e-12f);
  float4 o;  // exact fp32 division
  o.x = v.x / nr; o.y = v.y / nr; o.z = v.z / nr; o.w = v.w / nr;
  ((float4*)(f + (size_t)row * DIM))[lane] = o;
  double s2 = (double)o.x * o.x + (double)o.y * o.y + (double)o.z * o.z + (double)o.w * o.w;
  s2 = wave_sum64d(s2);
  if (lane == 0) sqd[row] = s2;
  uint2 w2;
  w2.x = (unsigned)f2bf(o.x) | ((unsigned)f2bf(o.y) << 16);
  w2.y = (unsigned)f2bf(o.z) | ((unsigned)f2bf(o.w) << 16);
  int T = row >> 6, rl = row & 63, g = lane >> 1, h = lane & 1;
  fb2[((size_t)T * 2048 + rl * 32 + (g ^ (rl & 31))) * 2 + h] = w2;
}

// ---------------- 2. MFMA bf16 candidate Gram + per-row top-8 ----------------
// grid 512: (row-block ib 0..127) x (j-split js 0..3). A-fragments in regs.
// Tile loop unrolled x2 over two STATIC B buffers -> all LDS addresses
// (B-frag reads, scatter bases, scan reads) are loop-invariant VGPRs.
// Scan granule rotated per row ((p+trow)&3) -> 8 lanes per 4-bank group
// (optimal); keys carry their own column index so rotation is free.
#define JSPAN (NROWS / NSPLIT)  // 2048
#define GTILES (JSPAN / 64)     // 32

__launch_bounds__(256, 2)
__global__ void k_gram(const uint4* __restrict__ fb, int* __restrict__ candp) {
  __shared__ uint4 Bsh0[2048];   // 32 KB
  __shared__ uint4 Bsh1[2048];   // 32 KB (stages A first)
  __shared__ float Csh[4096];    // 16 KB: per-wave C quadrants / merge

  const int t  = threadIdx.x;
  const int ib = blockIdx.x >> 2;
  const int js = blockIdx.x & 3;
  const int i0 = ib * 64;
  const int jbase = js * JSPAN;
  const int w = t >> 6, lane = t & 63;

  // DMA: A -> Bsh1, B tile0 -> Bsh0
  {
    const uint4* At = fb + (size_t)ib * 2048;
    const uint4* Bt = fb + (size_t)(js * 32) * 2048;
#pragma unroll
    for (int p = 0; p < 8; ++p) {
      int c = w * 8 + p;
      async_cp16(At + c * 64 + lane, &Bsh1[c * 64]);
      async_cp16(Bt + c * 64 + lane, &Bsh0[c * 64]);
    }
  }
  const int ihalf = w >> 1, jhalf = w & 1;
  const int m15 = lane & 15, quad = lane >> 4;

  __syncthreads();  // drain DMA: A + B0 visible

  // A-quadrant fragments -> registers
  bf16x8 areg[2][8];
#pragma unroll
  for (int s = 0; s < 2; ++s) {
    int ra = ihalf * 32 + s * 16 + m15;
#pragma unroll
    for (int kc = 0; kc < 8; ++kc)
      areg[s][kc] = ((const bf16x8*)Bsh1)[ra * 32 + ((kc * 4 + quad) ^ (ra & 31))];
  }
  __syncthreads();  // Bsh1 reusable

  // loop-invariant B-fragment indices (bf16x8 units)
  int bidx[2][8];
#pragma unroll
  for (int s = 0; s < 2; ++s) {
    int rb = jhalf * 32 + s * 16 + m15;
#pragma unroll
    for (int kc = 0; kc < 8; ++kc)
      bidx[s][kc] = rb * 32 + ((kc * 4 + quad) ^ (rb & 31));
  }
  // loop-invariant scatter bases (float units in Csw)
  int sbase[2][2];
#pragma unroll
  for (int si = 0; si < 2; ++si)
#pragma unroll
    for (int sj = 0; sj < 2; ++sj) {
      int lr0 = si * 16 + quad * 4;
      int lc = sj * 16 + m15;
      int gc = lc >> 2;
      sbase[si][sj] = lr0 * 32 + ((gc ^ (quad * 2)) << 2) + (lc & 3);
    }
  // loop-invariant rotated scan addresses + column bases
  const int trow = lane >> 1, thalf = lane & 1;
  const int skey = (trow >> 1) & 6;
  int scanoff[4], colp[4];
#pragma unroll
  for (int p = 0; p < 4; ++p) {
    int rot = (p + trow) & 3;
    int gcp = thalf * 4 + rot;
    scanoff[p] = trow * 32 + ((gcp ^ skey) << 2);
    colp[p] = thalf * 16 + rot * 4;   // bits 2..4 only
  }

  unsigned mk[NCAND];
#pragma unroll
  for (int k = 0; k < NCAND; ++k) mk[k] = 0u;
  float thr = -1e30f;
  float* Csw = Csh + w * 1024;

#define GRAM_BODY(JT, CUR, NXT)                                                \
  {                                                                            \
    const int jt = (JT);                                                       \
    if (jt + 1 < GTILES) {                                                     \
      const uint4* Bt = fb + (size_t)(js * 32 + jt + 1) * 2048;                \
      _Pragma("unroll")                                                        \
      for (int p = 0; p < 8; ++p) {                                            \
        int c = w * 8 + p;                                                     \
        async_cp16(Bt + c * 64 + lane, &NXT[c * 64]);                          \
      }                                                                        \
    }                                                                          \
    f32x4 acc[2][2];                                                           \
    _Pragma("unroll")                                                          \
    for (int si = 0; si < 2; ++si)                                             \
      _Pragma("unroll")                                                        \
      for (int sj = 0; sj < 2; ++sj) acc[si][sj] = (f32x4)(0.f);               \
    _Pragma("unroll")                                                          \
    for (int kc = 0; kc < 8; ++kc) {                                           \
      bf16x8 bv0 = ((const bf16x8*)CUR)[bidx[0][kc]];                          \
      bf16x8 bv1 = ((const bf16x8*)CUR)[bidx[1][kc]];                          \
      acc[0][0] = __builtin_amdgcn_mfma_f32_16x16x32_bf16(areg[0][kc], bv0, acc[0][0], 0, 0, 0); \
      acc[0][1] = __builtin_amdgcn_mfma_f32_16x16x32_bf16(areg[0][kc], bv1, acc[0][1], 0, 0, 0); \
      acc[1][0] = __builtin_amdgcn_mfma_f32_16x16x32_bf16(areg[1][kc], bv0, acc[1][0], 0, 0, 0); \
      acc[1][1] = __builtin_amdgcn_mfma_f32_16x16x32_bf16(areg[1][kc], bv1, acc[1][1], 0, 0, 0); \
    }                                                                          \
    _Pragma("unroll")                                                          \
    for (int si = 0; si < 2; ++si)                                             \
      _Pragma("unroll")                                                        \
      for (int sj = 0; sj < 2; ++sj) {                                         \
        _Pragma("unroll")                                                      \
        for (int r = 0; r < 4; ++r)                                            \
          Csw[sbase[si][sj] + r * 32] = acc[si][sj][r];                        \
      }                                                                        \
    {                                                                          \
      unsigned cb0 = (unsigned)(jt * 64 + jhalf * 32);                         \
      float4 v[4]; float g[4];                                                 \
      _Pragma("unroll")                                                        \
      for (int p = 0; p < 4; ++p) {                                            \
        v[p] = *(const float4*)&Csw[scanoff[p]];                               \
        g[p] = fmaxf(fmaxf(v[p].x, v[p].y), fmaxf(v[p].z, v[p].w));            \
      }                                                                        \
      float gmax = fmaxf(fmaxf(g[0], g[1]), fmaxf(g[2], g[3]));                \
      if (gmax > thr) {                                                        \
        _Pragma("unroll")                                                      \
        for (int p = 0; p < 4; ++p) {                                          \
          if (g[p] > thr) {                                                    \
            unsigned cbp = cb0 | (unsigned)colp[p];                            \
            float vv[4] = {v[p].x, v[p].y, v[p].z, v[p].w};                    \
            _Pragma("unroll")                                                  \
            for (int e = 0; e < 4; ++e) {                                      \
              unsigned ub = __float_as_uint(vv[e]);                            \
              unsigned key = ((ub ^ (unsigned)(((int)ub >> 31) | 0x80000000))  \
                              & ~2047u) | (cbp + (unsigned)e);                 \
              if (key > mk[NCAND - 1]) {                                       \
                mk[NCAND - 1] = key;                                           \
                _Pragma("unroll")                                              \
                for (int q = NCAND - 1; q >= 1; --q)                           \
                  if (mk[q] > mk[q - 1]) {                                     \
                    unsigned tm = mk[q]; mk[q] = mk[q - 1]; mk[q - 1] = tm;    \
                  }                                                            \
              }                                                                \
            }                                                                  \
          }                                                                    \
        }                                                                      \
      }                                                                        \
    }                                                                          \
    {  /* partner-segment union 8th-best -> tighter threshold (safe) */        \
      unsigned pk = mk[NCAND - 1] & ~2047u;                                    \
      unsigned qk = (unsigned)__shfl_xor((int)mk[NCAND - 1], 1, 64) & ~2047u;  \
      unsigned bk = pk > qk ? pk : qk;                                         \
      if (bk) {                                                                \
        unsigned xm = 0x80000000u | ~(unsigned)((int)bk >> 31);                \
        thr = __uint_as_float(bk ^ xm);                                        \
      }                                                                        \
    }                                                                          \
    __syncthreads();                                                           \
  }

  for (int jt2 = 0; jt2 < GTILES; jt2 += 2) {
    GRAM_BODY(jt2, Bsh0, Bsh1)
    GRAM_BODY(jt2 + 1, Bsh1, Bsh0)
  }
#undef GRAM_BODY

  // ---- merge 4 per-thread lists per row -> top-8 per (row, split) ----
  unsigned* mergeK = (unsigned*)Csh;  // [64][33]
  {
    int grow = ihalf * 32 + trow;
    int q = jhalf * 2 + thalf;
#pragma unroll
    for (int k = 0; k < NCAND; ++k) mergeK[grow * 33 + q * 8 + k] = mk[k];
  }
  __syncthreads();
  if (t < 64) {
    unsigned fk[NCAND];
#pragma unroll
    for (int k = 0; k < NCAND; ++k) fk[k] = 0u;
    for (int s = 0; s < 32; ++s) {
      unsigned kk = mergeK[t * 33 + s];
      if (kk > fk[NCAND - 1]) {
        fk[NCAND - 1] = kk;
#pragma unroll
        for (int q = NCAND - 1; q >= 1; --q)
          if (fk[q] > fk[q - 1]) { unsigned tm = fk[q]; fk[q] = fk[q - 1]; fk[q - 1] = tm; }
      }
    }
#pragma unroll
    for (int k = 0; k < NCAND; ++k)
      candp[(size_t)js * (NROWS * NCAND) + (size_t)(i0 + t) * NCAND + k] =
          jbase + (int)(fk[k] & 2047u);
  }
}

// ---------------- 3. fp64 exact refine (no divides: reads stored f) ----------------
__global__ void k_refine(const float* __restrict__ f, const double* __restrict__ sqd,
                         const int* __restrict__ candp, int* __restrict__ nbr) {
  const int row = blockIdx.x * 4 + (threadIdx.x >> 6);
  const int t = threadIdx.x & 63;
  const int c = t >> 1;        // candidate 0..31
  const int seg = t & 1;       // half of D
  const int split = c >> 3, slot = c & 7;
  int j = candp[(size_t)split * (NROWS * NCAND) + (size_t)row * NCAND + slot];
  const float4* fi4 = (const float4*)(f + (size_t)row * DIM) + seg * 32;
  const float4* fj4 = (const float4*)(f + (size_t)j * DIM) + seg * 32;
  double dot = 0.0;
#pragma unroll 8
  for (int d4 = 0; d4 < 32; ++d4) {
    float4 a = fi4[d4], b = fj4[d4];
    dot = fma((double)a.x, (double)b.x, dot);
    dot = fma((double)a.y, (double)b.y, dot);
    dot = fma((double)a.z, (double)b.z, dot);
    dot = fma((double)a.w, (double)b.w, dot);
  }
  dot += __shfl_xor(dot, 1, 64);
  double key = sqd[j] - 2.0 * dot;
  bool valid = (seg == 0) && (j != row);
  for (int s = 0; s < KNN; ++s) {
    double v = valid ? key : (double)INFINITY;
    int vj = valid ? j : 0x7fffffff;
#pragma unroll
    for (int m = 1; m < 64; m <<= 1) {
      double ov = __shfl_xor(v, m, 64);
      int oj = __shfl_xor(vj, m, 64);
      if (ov < v || (ov == v && oj < vj)) { v = ov; vj = oj; }
    }
    if (valid && vj == j) valid = false;
    if (t == 0) nbr[(size_t)row * 8 + s] = vj;
  }
}

// ---------------- 4. persistent solver (R7-proven flat barrier) ----------------
// 256 blocks x 512 threads (8 waves, 4 rows/wave, lane=class). Softmax
// without max-sub (logits in [-23,5]). E = -sum lse (LAM=1). Last-block E
// reduction by one wave.
__global__ void k_solve(const float* __restrict__ scores,
                        const int* __restrict__ nbr,
                        float* __restrict__ Ya, float* __restrict__ Yb,
                        float* __restrict__ out, GS* __restrict__ gs) {
  const int b = blockIdx.x;
  const int w = threadIdx.x >> 6, lane = threadIdx.x & 63;
  const int row0 = b * 32 + w * 4;
  __shared__ int nbl[32][5];
  __shared__ double sE[8];
  __shared__ int isLast, sflag;

  if (threadIdx.x < 160)
    nbl[threadIdx.x / 5][threadIdx.x % 5] =
        nbr[(size_t)(b * 32 + threadIdx.x / 5) * 8 + (threadIdx.x % 5)];

  float u[4], y[4];
#pragma unroll
  for (int r = 0; r < 4; ++r)
    u[r] = -logf(scores[(size_t)(row0 + r) * NCLS + lane] + 1e-10f);
#pragma unroll
  for (int r = 0; r < 4; ++r) {
    float e = expf(-u[r]);
    float sum = wave_sum64(e);
    y[r] = e / sum;
    Ya[(size_t)(row0 + r) * NCLS + lane] = y[r];
  }
  __syncthreads();  // nbl ready; own Y0 stores complete

  // hoist neighbor element-offsets into registers
  int nboff[4][KNN];
#pragma unroll
  for (int r = 0; r < 4; ++r)
#pragma unroll
    for (int k = 0; k < KNN; ++k)
      nboff[r][k] = nbl[w * 4 + r][k] * NCLS + lane;

  int mygen = 1;
  // grid barrier: publish Y0
  if (threadIdx.x == 0) {
    __threadfence();
    int old = atomicAdd(&gs->count, 1);
    if (old == PBLK - 1) { gs->count = 0; __threadfence(); atomicAdd(&gs->gen, 1); }
    while (__hip_atomic_load(&gs->gen, __ATOMIC_ACQUIRE, __HIP_MEMORY_SCOPE_AGENT) < mygen)
      __builtin_amdgcn_s_sleep(1);
    __threadfence();
  }
  __syncthreads();
  ++mygen;

  for (int iter = 0; iter < MAXSTEPS; ++iter) {
    const float* __restrict__ Yin = (iter & 1) ? Yb : Ya;
    float* __restrict__ Yout = (iter & 1) ? Ya : Yb;
    double ew = 0.0;
#pragma unroll
    for (int r = 0; r < 4; ++r) {
      float pw = 0.f;
#pragma unroll
      for (int k = 0; k < KNN; ++k) pw += Yin[nboff[r][k]];
      float e = expf(pw - u[r]);
      float sum = wave_sum64(e);
      y[r] = e / sum;
      Yout[(size_t)(row0 + r) * NCLS + lane] = y[r];
      ew += -(double)logf(sum);
    }
    if (lane == 0) sE[w] = ew;
    __syncthreads();  // sE ready + all Y stores drained
    if (threadIdx.x == 0) {
      gs->Epart[b] = ((sE[0] + sE[1]) + (sE[2] + sE[3])) +
                     ((sE[4] + sE[5]) + (sE[6] + sE[7]));
      __threadfence();  // release Epart + this block's Y
      int old = atomicAdd(&gs->count, 1);
      isLast = (old == PBLK - 1) ? 1 : 0;
    }
    __syncthreads();
    if (isLast && threadIdx.x < 64) {  // one wave: parallel E reduction
      __threadfence();  // acquire all Epart
      double s = (gs->Epart[lane] + gs->Epart[lane + 64]) +
                 (gs->Epart[lane + 128] + gs->Epart[lane + 192]);
      s = wave_sum64d(s);
      if (lane == 0) {
        double E = s;
        int conv = (iter > 1) && (fabs(E - gs->Eold) <= 1e-8 * fabs(gs->Eold));
        gs->flag = conv;
        if (!conv) gs->Eold = E;
        gs->count = 0;
        __threadfence();
        atomicAdd(&gs->gen, 1);  // release epoch
      }
    }
    if (threadIdx.x == 0) {
      while (__hip_atomic_load(&gs->gen, __ATOMIC_ACQUIRE, __HIP_MEMORY_SCOPE_AGENT) < mygen)
        __builtin_amdgcn_s_sleep(1);
      __threadfence();  // acquire other blocks' Y + flag
      sflag = gs->flag;
    }
    __syncthreads();
    ++mygen;
    if (sflag) break;  // uniform across grid
  }

#pragma unroll
  for (int r = 0; r < 4; ++r)
    out[(size_t)(row0 + r) * NCLS + lane] = y[r];
}

// ---------------- 0. state init ----------------
__global__ void k_init(GS* gs) {
  if (threadIdx.x == 0) {
    gs->Eold = (double)INFINITY;
    gs->count = 0; gs->gen = 0; gs->flag = 0;
  }
}

extern "C" void kernel_launch(void* const* d_in, const int* in_sizes, int n_in,
                              void* d_out, int out_size, void* d_ws, size_t ws_size,
                              hipStream_t stream) {
  (void)in_sizes; (void)n_in; (void)out_size; (void)ws_size;
  const float* scores = (const float*)d_in[0];
  const float* feats  = (const float*)d_in[1];
  float* out = (float*)d_out;
  char* ws = (char*)d_ws;
  // workspace layout (256B-aligned); total ~14.0 MB (proven budget >= 16.07 MB)
  uint4*  fb    = (uint4*)(ws + 0);          //  4 MB pre-swizzled bf16 tiles
  float*  f     = (float*)(ws + 4194304);    //  8 MB fp32 normalized (dies after refine)
  float*  Ya    = (float*)(ws + 4194304);    //  2 MB (aliases f; live from k_solve)
  float*  Yb    = (float*)(ws + 6291456);    //  2 MB (aliases f)
  double* sqd   = (double*)(ws + 12582912);  // 64 KB
  int*    candp = (int*)(ws + 12648448);     //  1 MB (4 splits x 8192 x 8)
  int*    nbr   = (int*)(ws + 13697024);     // 256 KB
  GS*     gs    = (GS*)(ws + 13959168);      // ~2.1 KB

  k_init<<<1, 64, 0, stream>>>(gs);
  k_normalize<<<NROWS / 4, 256, 0, stream>>>(feats, (uint2*)fb, f, sqd);
  k_gram<<<(NROWS / 64) * NSPLIT, 256, 0, stream>>>(fb, candp);
  k_refine<<<NROWS / 4, 256, 0, stream>>>(f, sqd, candp, nbr);
  k_solve<<<PBLK, 512, 0, stream>>>(scores, nbr, Ya, Yb, out, gs);
}

// Round 10
// 269.393 us; speedup vs baseline: 2.0613x; 1.3978x over previous
//
#include <hip/hip_runtime.h>
#include <math.h>

#define NROWS 8192
#define DIM   256
#define NCLS  64
#define KNN   5
#define NCAND 8      // per (row, j-split)
#define NSPLIT 4
#define MAXSTEPS 100
#define PBLK 256     // persistent-solver blocks: 1 per CU -> co-residency guaranteed

struct GS {
  double Eold;
  double Epart[PBLK];
  int pad0[30];
  int count; int pad1[31];   // fan-in line
  int gen;   int pad2[31];   // release line (separate: spinners don't poll fan-in)
  int flag;  int pad3[31];
};

typedef __attribute__((ext_vector_type(8))) short bf16x8;
typedef __attribute__((ext_vector_type(4))) float f32x4;

typedef __attribute__((address_space(1))) unsigned int glb_u32_t;
typedef __attribute__((address_space(3))) unsigned int lds_u32_t;
// async global->LDS DMA, 16 B/lane; LDS dest = wave-uniform base + lane*16
__device__ __forceinline__ void async_cp16(const uint4* g, uint4* l) {
  __builtin_amdgcn_global_load_lds((const glb_u32_t*)(const unsigned int*)g,
                                   (lds_u32_t*)(unsigned int*)l, 16, 0, 0);
}

// agent-scope relaxed ops: data is coherent at L3 by construction (sc0 sc1),
// so no buffer_wbl2 / buffer_inv fences are ever needed.
__device__ __forceinline__ float aloadf(const float* p) {
  return __hip_atomic_load(p, __ATOMIC_RELAXED, __HIP_MEMORY_SCOPE_AGENT);
}
__device__ __forceinline__ void astoref(float* p, float v) {
  __hip_atomic_store(p, v, __ATOMIC_RELAXED, __HIP_MEMORY_SCOPE_AGENT);
}
__device__ __forceinline__ double aloadd(const double* p) {
  return __hip_atomic_load(p, __ATOMIC_RELAXED, __HIP_MEMORY_SCOPE_AGENT);
}
__device__ __forceinline__ void astored(double* p, double v) {
  __hip_atomic_store(p, v, __ATOMIC_RELAXED, __HIP_MEMORY_SCOPE_AGENT);
}
__device__ __forceinline__ int aloadi(const int* p) {
  return __hip_atomic_load(p, __ATOMIC_RELAXED, __HIP_MEMORY_SCOPE_AGENT);
}
__device__ __forceinline__ void astorei(int* p, int v) {
  __hip_atomic_store(p, v, __ATOMIC_RELAXED, __HIP_MEMORY_SCOPE_AGENT);
}

// ---------------- wave (64-lane) reductions ----------------
__device__ __forceinline__ float wave_sum64(float v) {
#pragma unroll
  for (int m = 32; m >= 1; m >>= 1) v += __shfl_xor(v, m, 64);
  return v;
}
__device__ __forceinline__ double wave_sum64d(double v) {
#pragma unroll
  for (int m = 32; m >= 1; m >>= 1) v += __shfl_xor(v, m, 64);
  return v;
}

__device__ __forceinline__ unsigned short f2bf(float x) {  // RNE bf16
  unsigned u = __float_as_uint(x);
  u += 0x7FFFu + ((u >> 16) & 1u);
  return (unsigned short)(u >> 16);
}

// ---------------- 1. normalize: bf16 swizzled tiles + fp32 f + sqd ----------------
// fb layout (uint4 granules = 8 bf16 dims): row r -> tile T=r>>6, local row
// rl=r&63, granule g: fb_uint4[T*2048 + rl*32 + (g ^ (rl&31))].
__global__ void k_normalize(const float* __restrict__ feats, uint2* __restrict__ fb2,
                            float* __restrict__ f, double* __restrict__ sqd) {
  int row  = blockIdx.x * 4 + (threadIdx.x >> 6);
  int lane = threadIdx.x & 63;
  float4 v = ((const float4*)(feats + (size_t)row * DIM))[lane];
  double ss = (double)v.x * v.x + (double)v.y * v.y + (double)v.z * v.z + (double)v.w * v.w;
  ss = wave_sum64d(ss);
  float nr = fmaxf((float)sqrt(ss), 1e-12f);
  float4 o;  // exact fp32 division
  o.x = v.x / nr; o.y = v.y / nr; o.z = v.z / nr; o.w = v.w / nr;
  ((float4*)(f + (size_t)row * DIM))[lane] = o;
  double s2 = (double)o.x * o.x + (double)o.y * o.y + (double)o.z * o.z + (double)o.w * o.w;
  s2 = wave_sum64d(s2);
  if (lane == 0) sqd[row] = s2;
  uint2 w2;
  w2.x = (unsigned)f2bf(o.x) | ((unsigned)f2bf(o.y) << 16);
  w2.y = (unsigned)f2bf(o.z) | ((unsigned)f2bf(o.w) << 16);
  int T = row >> 6, rl = row & 63, g = lane >> 1, h = lane & 1;
  fb2[((size_t)T * 2048 + rl * 32 + (g ^ (rl & 31))) * 2 + h] = w2;
}

// ---------------- 2. MFMA bf16 candidate Gram + per-row top-8 ----------------
// R7-proven kernel (measured 108 us): A-fragments in regs, double-buffered B
// via async DMA -> one barrier per tile, wave-local branchy top-k. Inline
// address math (R9's precomputed-index variant regressed on VGPR pressure).
#define JSPAN (NROWS / NSPLIT)  // 2048
#define GTILES (JSPAN / 64)     // 32

__launch_bounds__(256, 2)
__global__ void k_gram(const uint4* __restrict__ fb, int* __restrict__ candp) {
  __shared__ uint4 Bsh4[2][2048];   // 64 KB; buf1 stages A first
  __shared__ float Csh[4096];       // 16 KB: per-wave C quadrants / merge

  const int t  = threadIdx.x;
  const int ib = blockIdx.x >> 2;
  const int js = blockIdx.x & 3;
  const int i0 = ib * 64;
  const int jbase = js * JSPAN;
  const int w = t >> 6, lane = t & 63;

  // DMA: A -> buf1, B tile0 -> buf0
  {
    const uint4* At = fb + (size_t)ib * 2048;
    const uint4* Bt = fb + (size_t)(js * 32) * 2048;
#pragma unroll
    for (int p = 0; p < 8; ++p) {
      int c = w * 8 + p;
      async_cp16(At + c * 64 + lane, &Bsh4[1][c * 64]);
      async_cp16(Bt + c * 64 + lane, &Bsh4[0][c * 64]);
    }
  }
  const int ihalf = w >> 1, jhalf = w & 1;
  const int m15 = lane & 15, quad = lane >> 4;

  __syncthreads();  // drain DMA: A + B0 visible

  // A-quadrant fragments -> registers
  bf16x8 areg[2][8];
#pragma unroll
  for (int s = 0; s < 2; ++s) {
    int ra = ihalf * 32 + s * 16 + m15;
#pragma unroll
    for (int kc = 0; kc < 8; ++kc)
      areg[s][kc] = ((const bf16x8*)Bsh4[1])[ra * 32 + ((kc * 4 + quad) ^ (ra & 31))];
  }
  __syncthreads();  // buf1 reusable

  unsigned mk[NCAND];
#pragma unroll
  for (int k = 0; k < NCAND; ++k) mk[k] = 0u;
  float thr = -1e30f;

  const int trow = lane >> 1;   // local row 0..31 of wave quadrant
  const int thalf = lane & 1;   // 16-col half
  float* Csw = Csh + w * 1024;

  for (int jt = 0; jt < GTILES; ++jt) {
    const int cbuf = jt & 1;
    if (jt > 0) __syncthreads();
    if (jt + 1 < GTILES) {
      const uint4* Bt = fb + (size_t)(js * 32 + jt + 1) * 2048;
#pragma unroll
      for (int p = 0; p < 8; ++p) {
        int c = w * 8 + p;
        async_cp16(Bt + c * 64 + lane, &Bsh4[1 - cbuf][c * 64]);
      }
    }

    f32x4 acc[2][2];
#pragma unroll
    for (int si = 0; si < 2; ++si)
#pragma unroll
      for (int sj = 0; sj < 2; ++sj) acc[si][sj] = (f32x4)(0.f);

#pragma unroll
    for (int kc = 0; kc < 8; ++kc) {
      bf16x8 bv[2];
#pragma unroll
      for (int s = 0; s < 2; ++s) {
        int rb = jhalf * 32 + s * 16 + m15;
        bv[s] = ((const bf16x8*)Bsh4[cbuf])[rb * 32 + ((kc * 4 + quad) ^ (rb & 31))];
      }
      acc[0][0] = __builtin_amdgcn_mfma_f32_16x16x32_bf16(areg[0][kc], bv[0], acc[0][0], 0, 0, 0);
      acc[0][1] = __builtin_amdgcn_mfma_f32_16x16x32_bf16(areg[0][kc], bv[1], acc[0][1], 0, 0, 0);
      acc[1][0] = __builtin_amdgcn_mfma_f32_16x16x32_bf16(areg[1][kc], bv[0], acc[1][0], 0, 0, 0);
      acc[1][1] = __builtin_amdgcn_mfma_f32_16x16x32_bf16(areg[1][kc], bv[1], acc[1][1], 0, 0, 0);
    }

    // C scatter -> wave-local quadrant (32x32); swizzle key quad*2 pairs the
    // 4 stores of each acc float4 (+0/+128/+256/+384 B).
#pragma unroll
    for (int si = 0; si < 2; ++si)
#pragma unroll
      for (int sj = 0; sj < 2; ++sj) {
        int lr0 = si * 16 + quad * 4;
        int key = quad * 2;
        int lc = sj * 16 + m15;
        int gc = lc >> 2;
        int base = lr0 * 32 + ((gc ^ key) << 2) + (lc & 3);
#pragma unroll
        for (int r = 0; r < 4; ++r)
          Csw[base + r * 32] = acc[si][sj][r];
      }

    // wave-local top-8: lane scans (row trow, cols thalf*16..+15)
    {
      int cb0 = jt * 64 + jhalf * 32;
      int skey = (trow >> 1) & 6;
#pragma unroll
      for (int p = 0; p < 4; ++p) {
        int gc = thalf * 4 + p;
        float4 v = *(const float4*)&Csw[trow * 32 + ((gc ^ skey) << 2)];
        float g4 = fmaxf(fmaxf(v.x, v.y), fmaxf(v.z, v.w));
        if (g4 > thr) {
          int cbase = cb0 + gc * 4;
          float vv[4] = {v.x, v.y, v.z, v.w};
#pragma unroll
          for (int e = 0; e < 4; ++e) {
            unsigned ub = __float_as_uint(vv[e]);
            unsigned key = ((ub ^ (unsigned)(((int)ub >> 31) | 0x80000000)) & ~2047u)
                           | (unsigned)(cbase + e);
            if (key > mk[NCAND - 1]) {
              mk[NCAND - 1] = key;
#pragma unroll
              for (int q = NCAND - 1; q >= 1; --q)
                if (mk[q] > mk[q - 1]) { unsigned tm = mk[q]; mk[q] = mk[q - 1]; mk[q - 1] = tm; }
            }
          }
          unsigned kb = mk[NCAND - 1] & ~2047u;
          if (kb) {  // conservative float threshold from 8th-best key
            unsigned xm = 0x80000000u | ~(unsigned)((int)kb >> 31);
            thr = __uint_as_float(kb ^ xm);
          }
        }
      }
    }
  }

  // ---- merge 4 per-thread lists per row -> top-8 per (row, split) ----
  __syncthreads();
  unsigned* mergeK = (unsigned*)Csh;  // [64][33]
  {
    int grow = ihalf * 32 + trow;
    int q = jhalf * 2 + thalf;
#pragma unroll
    for (int k = 0; k < NCAND; ++k) mergeK[grow * 33 + q * 8 + k] = mk[k];
  }
  __syncthreads();
  if (t < 64) {
    unsigned fk[NCAND];
#pragma unroll
    for (int k = 0; k < NCAND; ++k) fk[k] = 0u;
    for (int s = 0; s < 32; ++s) {
      unsigned kk = mergeK[t * 33 + s];
      if (kk > fk[NCAND - 1]) {
        fk[NCAND - 1] = kk;
#pragma unroll
        for (int q = NCAND - 1; q >= 1; --q)
          if (fk[q] > fk[q - 1]) { unsigned tm = fk[q]; fk[q] = fk[q - 1]; fk[q - 1] = tm; }
      }
    }
#pragma unroll
    for (int k = 0; k < NCAND; ++k)
      candp[(size_t)js * (NROWS * NCAND) + (size_t)(i0 + t) * NCAND + k] =
          jbase + (int)(fk[k] & 2047u);
  }
}

// ---------------- 3. fp64 exact refine (no divides: reads stored f) ----------------
__global__ void k_refine(const float* __restrict__ f, const double* __restrict__ sqd,
                         const int* __restrict__ candp, int* __restrict__ nbr) {
  const int row = blockIdx.x * 4 + (threadIdx.x >> 6);
  const int t = threadIdx.x & 63;
  const int c = t >> 1;        // candidate 0..31
  const int seg = t & 1;       // half of D
  const int split = c >> 3, slot = c & 7;
  int j = candp[(size_t)split * (NROWS * NCAND) + (size_t)row * NCAND + slot];
  const float4* fi4 = (const float4*)(f + (size_t)row * DIM) + seg * 32;
  const float4* fj4 = (const float4*)(f + (size_t)j * DIM) + seg * 32;
  double dot = 0.0;
#pragma unroll 8
  for (int d4 = 0; d4 < 32; ++d4) {
    float4 a = fi4[d4], b = fj4[d4];
    dot = fma((double)a.x, (double)b.x, dot);
    dot = fma((double)a.y, (double)b.y, dot);
    dot = fma((double)a.z, (double)b.z, dot);
    dot = fma((double)a.w, (double)b.w, dot);
  }
  dot += __shfl_xor(dot, 1, 64);
  double key = sqd[j] - 2.0 * dot;
  bool valid = (seg == 0) && (j != row);
  for (int s = 0; s < KNN; ++s) {
    double v = valid ? key : (double)INFINITY;
    int vj = valid ? j : 0x7fffffff;
#pragma unroll
    for (int m = 1; m < 64; m <<= 1) {
      double ov = __shfl_xor(v, m, 64);
      int oj = __shfl_xor(vj, m, 64);
      if (ov < v || (ov == v && oj < vj)) { v = ov; vj = oj; }
    }
    if (valid && vj == j) valid = false;
    if (t == 0) nbr[(size_t)row * 8 + s] = vj;
  }
}

// ---------------- 4. persistent solver: Y0 + all iterations + out ----------------
// 256 blocks x 512 threads (8 waves, 4 rows/wave, lane=class). All cross-block
// traffic (Y, Epart, count/gen/flag) is agent-scope relaxed -> no buffer_wbl2 /
// buffer_inv; pre-arrival ordering is a workgroup release (vmcnt wait only).
// 2 __syncthreads per iter; E-reduce + convergence by wave 0 of last block.
__global__ void k_solve(const float* __restrict__ scores,
                        const int* __restrict__ nbr,
                        float* __restrict__ Ya, float* __restrict__ Yb,
                        float* __restrict__ out, GS* __restrict__ gs) {
  const int b = blockIdx.x;
  const int w = threadIdx.x >> 6, lane = threadIdx.x & 63;
  const int row0 = b * 32 + w * 4;
  __shared__ int nbl[32][5];
  __shared__ double sE[8];
  __shared__ int sflag;

  if (threadIdx.x < 160)
    nbl[threadIdx.x / 5][threadIdx.x % 5] =
        nbr[(size_t)(b * 32 + threadIdx.x / 5) * 8 + (threadIdx.x % 5)];

  float u[4], y[4];
#pragma unroll
  for (int r = 0; r < 4; ++r)
    u[r] = -logf(scores[(size_t)(row0 + r) * NCLS + lane] + 1e-10f);
#pragma unroll
  for (int r = 0; r < 4; ++r) {
    float e = expf(-u[r]);
    float sum = wave_sum64(e);
    y[r] = e / sum;
    astoref(&Ya[(size_t)(row0 + r) * NCLS + lane], y[r]);
  }
  __syncthreads();  // nbl ready

  // hoist neighbor element-offsets into registers
  int nboff[4][KNN];
#pragma unroll
  for (int r = 0; r < 4; ++r)
#pragma unroll
    for (int k = 0; k < KNN; ++k)
      nboff[r][k] = nbl[w * 4 + r][k] * NCLS + lane;

  int mygen = 1;
  // grid barrier: publish Y0
  if (threadIdx.x == 0) {
    __builtin_amdgcn_fence(__ATOMIC_RELEASE, "workgroup");  // drain Y0 stores (vmcnt)
    int old = __hip_atomic_fetch_add(&gs->count, 1, __ATOMIC_RELAXED,
                                     __HIP_MEMORY_SCOPE_AGENT);
    if (old == PBLK - 1) {
      astorei(&gs->count, 0);
      __builtin_amdgcn_fence(__ATOMIC_RELEASE, "workgroup");
      astorei(&gs->gen, mygen);
    }
    while (aloadi(&gs->gen) < mygen) __builtin_amdgcn_s_sleep(1);
  }
  __syncthreads();
  ++mygen;

  for (int iter = 0; iter < MAXSTEPS; ++iter) {
    const float* __restrict__ Yin = (iter & 1) ? Yb : Ya;
    float* __restrict__ Yout = (iter & 1) ? Ya : Yb;
    double ew = 0.0;
#pragma unroll
    for (int r = 0; r < 4; ++r) {
      float pw = 0.f;
#pragma unroll
      for (int k = 0; k < KNN; ++k) pw += aloadf(&Yin[nboff[r][k]]);
      float e = expf(pw - u[r]);
      float sum = wave_sum64(e);
      y[r] = e / sum;
      astoref(&Yout[(size_t)(row0 + r) * NCLS + lane], y[r]);
      ew += -(double)logf(sum);
    }
    if (lane == 0) sE[w] = ew;
    __syncthreads();  // sE visible to wave 0
    if (w == 0) {
      double be = (lane < 8) ? sE[lane] : 0.0;
      be = wave_sum64d(be);
      int last = 0;
      if (lane == 0) {
        astored(&gs->Epart[b], be);
        __builtin_amdgcn_fence(__ATOMIC_RELEASE, "workgroup");  // drain Y + Epart (vmcnt)
        int old = __hip_atomic_fetch_add(&gs->count, 1, __ATOMIC_RELAXED,
                                         __HIP_MEMORY_SCOPE_AGENT);
        last = (old == PBLK - 1);
      }
      last = __shfl(last, 0, 64);
      if (last) {  // one wave: parallel E reduction + convergence + release
        double s = 0.0;
#pragma unroll
        for (int i = 0; i < 4; ++i) s += aloadd(&gs->Epart[lane + 64 * i]);
        s = wave_sum64d(s);
        if (lane == 0) {
          double eo = aloadd(&gs->Eold);
          int conv = (iter > 1) && (fabs(s - eo) <= 1e-8 * fabs(eo));
          astorei(&gs->flag, conv);
          if (!conv) astored(&gs->Eold, s);
          astorei(&gs->count, 0);
          __builtin_amdgcn_fence(__ATOMIC_RELEASE, "workgroup");
          astorei(&gs->gen, mygen);  // release epoch (single writer)
        }
      }
      if (lane == 0) {
        while (aloadi(&gs->gen) < mygen) __builtin_amdgcn_s_sleep(1);
        sflag = aloadi(&gs->flag);
      }
    }
    __syncthreads();
    ++mygen;
    if (sflag) break;  // uniform across grid
  }

  // y regs hold the final iteration's values for this block's rows
#pragma unroll
  for (int r = 0; r < 4; ++r)
    out[(size_t)(row0 + r) * NCLS + lane] = y[r];
}

// ---------------- 0. state init ----------------
__global__ void k_init(GS* gs) {
  if (threadIdx.x == 0) {
    gs->Eold = (double)INFINITY;
    gs->count = 0; gs->gen = 0; gs->flag = 0;
  }
}

extern "C" void kernel_launch(void* const* d_in, const int* in_sizes, int n_in,
                              void* d_out, int out_size, void* d_ws, size_t ws_size,
                              hipStream_t stream) {
  (void)in_sizes; (void)n_in; (void)out_size; (void)ws_size;
  const float* scores = (const float*)d_in[0];
  const float* feats  = (const float*)d_in[1];
  float* out = (float*)d_out;
  char* ws = (char*)d_ws;
  // workspace layout (256B-aligned); total ~14.0 MB
  uint4*  fb    = (uint4*)(ws + 0);          //  4 MB pre-swizzled bf16 tiles
  float*  f     = (float*)(ws + 4194304);    //  8 MB fp32 normalized (dies after refine)
  float*  Ya    = (float*)(ws + 4194304);    //  2 MB (aliases f; live from k_solve)
  float*  Yb    = (float*)(ws + 6291456);    //  2 MB (aliases f)
  double* sqd   = (double*)(ws + 12582912);  // 64 KB
  int*    candp = (int*)(ws + 12648448);     //  1 MB (4 splits x 8192 x 8)
  int*    nbr   = (int*)(ws + 13697024);     // 256 KB
  GS*     gs    = (GS*)(ws + 13959168);      // ~2.6 KB

  k_init<<<1, 64, 0, stream>>>(gs);
  k_normalize<<<NROWS / 4, 256, 0, stream>>>(feats, (uint2*)fb, f, sqd);
  k_gram<<<(NROWS / 64) * NSPLIT, 256, 0, stream>>>(fb, candp);
  k_refine<<<NROWS / 4, 256, 0, stream>>>(f, sqd, candp, nbr);
  k_solve<<<PBLK, 512, 0, stream>>>(scores, nbr, Ya, Yb, out, gs);
}

// Round 11
// 262.762 us; speedup vs baseline: 2.1133x; 1.0252x over previous
//
#include <hip/hip_runtime.h>
#include <math.h>

#define NROWS 8192
#define DIM   256
#define NCLS  64
#define KNN   5
#define NCAND 8      // per (row, j-split)
#define NSPLIT 4
#define MAXSTEPS 100
#define PBLK 256     // persistent-solver blocks: 1 per CU -> co-residency guaranteed

struct GS {
  double Eold;
  double Epart[PBLK];
  int pad0[30];
  int gcnt[16 * 32];         // 16 group fan-in lines (128B apart)
  int root; int pad1[31];    // root fan-in line
  int gen;  int pad2[31];    // release line
  int flag; int pad3[31];
};

typedef __attribute__((ext_vector_type(8))) short bf16x8;
typedef __attribute__((ext_vector_type(4))) float f32x4;

typedef __attribute__((address_space(1))) unsigned int glb_u32_t;
typedef __attribute__((address_space(3))) unsigned int lds_u32_t;
// async global->LDS DMA, 16 B/lane; LDS dest = wave-uniform base + lane*16
__device__ __forceinline__ void async_cp16(const uint4* g, uint4* l) {
  __builtin_amdgcn_global_load_lds((const glb_u32_t*)(const unsigned int*)g,
                                   (lds_u32_t*)(unsigned int*)l, 16, 0, 0);
}

// agent-scope relaxed ops: coherent at L3 by construction -> no wbl2/inv fences
__device__ __forceinline__ float aloadf(const float* p) {
  return __hip_atomic_load(p, __ATOMIC_RELAXED, __HIP_MEMORY_SCOPE_AGENT);
}
__device__ __forceinline__ void astoref(float* p, float v) {
  __hip_atomic_store(p, v, __ATOMIC_RELAXED, __HIP_MEMORY_SCOPE_AGENT);
}
__device__ __forceinline__ double aloadd(const double* p) {
  return __hip_atomic_load(p, __ATOMIC_RELAXED, __HIP_MEMORY_SCOPE_AGENT);
}
__device__ __forceinline__ void astored(double* p, double v) {
  __hip_atomic_store(p, v, __ATOMIC_RELAXED, __HIP_MEMORY_SCOPE_AGENT);
}
__device__ __forceinline__ int aloadi(const int* p) {
  return __hip_atomic_load(p, __ATOMIC_RELAXED, __HIP_MEMORY_SCOPE_AGENT);
}
__device__ __forceinline__ void astorei(int* p, int v) {
  __hip_atomic_store(p, v, __ATOMIC_RELAXED, __HIP_MEMORY_SCOPE_AGENT);
}
__device__ __forceinline__ int afetchadd(int* p) {
  return __hip_atomic_fetch_add(p, 1, __ATOMIC_RELAXED, __HIP_MEMORY_SCOPE_AGENT);
}

// ---------------- wave (64-lane) reductions ----------------
__device__ __forceinline__ float wave_sum64(float v) {
#pragma unroll
  for (int m = 32; m >= 1; m >>= 1) v += __shfl_xor(v, m, 64);
  return v;
}
__device__ __forceinline__ double wave_sum64d(double v) {
#pragma unroll
  for (int m = 32; m >= 1; m >>= 1) v += __shfl_xor(v, m, 64);
  return v;
}

__device__ __forceinline__ unsigned short f2bf(float x) {  // RNE bf16
  unsigned u = __float_as_uint(x);
  u += 0x7FFFu + ((u >> 16) & 1u);
  return (unsigned short)(u >> 16);
}

// ---------------- 1. normalize: bf16 swizzled tiles + fp32 f + sqd ----------------
// fb layout (uint4 granules = 8 bf16 dims): row r -> tile T=r>>6, local row
// rl=r&63, granule g: fb_uint4[T*2048 + rl*32 + (g ^ (rl&31))].
__global__ void k_normalize(const float* __restrict__ feats, uint2* __restrict__ fb2,
                            float* __restrict__ f, double* __restrict__ sqd) {
  int row  = blockIdx.x * 4 + (threadIdx.x >> 6);
  int lane = threadIdx.x & 63;
  float4 v = ((const float4*)(feats + (size_t)row * DIM))[lane];
  double ss = (double)v.x * v.x + (double)v.y * v.y + (double)v.z * v.z + (double)v.w * v.w;
  ss = wave_sum64d(ss);
  float nr = fmaxf((float)sqrt(ss), 1e-12f);
  float4 o;  // exact fp32 division
  o.x = v.x / nr; o.y = v.y / nr; o.z = v.z / nr; o.w = v.w / nr;
  ((float4*)(f + (size_t)row * DIM))[lane] = o;
  double s2 = (double)o.x * o.x + (double)o.y * o.y + (double)o.z * o.z + (double)o.w * o.w;
  s2 = wave_sum64d(s2);
  if (lane == 0) sqd[row] = s2;
  uint2 w2;
  w2.x = (unsigned)f2bf(o.x) | ((unsigned)f2bf(o.y) << 16);
  w2.y = (unsigned)f2bf(o.z) | ((unsigned)f2bf(o.w) << 16);
  int T = row >> 6, rl = row & 63, g = lane >> 1, h = lane & 1;
  fb2[((size_t)T * 2048 + rl * 32 + (g ^ (rl & 31))) * 2 + h] = w2;
}

// ---------------- 2. MFMA bf16 candidate Gram + per-row top-8 ----------------
// R7/R10-proven kernel (measured 108 us): A-fragments in regs, double-buffered
// B via async DMA -> one barrier per tile, wave-local branchy top-k.
#define JSPAN (NROWS / NSPLIT)  // 2048
#define GTILES (JSPAN / 64)     // 32

__launch_bounds__(256, 2)
__global__ void k_gram(const uint4* __restrict__ fb, int* __restrict__ candp) {
  __shared__ uint4 Bsh4[2][2048];   // 64 KB; buf1 stages A first
  __shared__ float Csh[4096];       // 16 KB: per-wave C quadrants / merge

  const int t  = threadIdx.x;
  const int ib = blockIdx.x >> 2;
  const int js = blockIdx.x & 3;
  const int i0 = ib * 64;
  const int jbase = js * JSPAN;
  const int w = t >> 6, lane = t & 63;

  // DMA: A -> buf1, B tile0 -> buf0
  {
    const uint4* At = fb + (size_t)ib * 2048;
    const uint4* Bt = fb + (size_t)(js * 32) * 2048;
#pragma unroll
    for (int p = 0; p < 8; ++p) {
      int c = w * 8 + p;
      async_cp16(At + c * 64 + lane, &Bsh4[1][c * 64]);
      async_cp16(Bt + c * 64 + lane, &Bsh4[0][c * 64]);
    }
  }
  const int ihalf = w >> 1, jhalf = w & 1;
  const int m15 = lane & 15, quad = lane >> 4;

  __syncthreads();  // drain DMA: A + B0 visible

  // A-quadrant fragments -> registers
  bf16x8 areg[2][8];
#pragma unroll
  for (int s = 0; s < 2; ++s) {
    int ra = ihalf * 32 + s * 16 + m15;
#pragma unroll
    for (int kc = 0; kc < 8; ++kc)
      areg[s][kc] = ((const bf16x8*)Bsh4[1])[ra * 32 + ((kc * 4 + quad) ^ (ra & 31))];
  }
  __syncthreads();  // buf1 reusable

  unsigned mk[NCAND];
#pragma unroll
  for (int k = 0; k < NCAND; ++k) mk[k] = 0u;
  float thr = -1e30f;

  const int trow = lane >> 1;   // local row 0..31 of wave quadrant
  const int thalf = lane & 1;   // 16-col half
  float* Csw = Csh + w * 1024;

  for (int jt = 0; jt < GTILES; ++jt) {
    const int cbuf = jt & 1;
    if (jt > 0) __syncthreads();
    if (jt + 1 < GTILES) {
      const uint4* Bt = fb + (size_t)(js * 32 + jt + 1) * 2048;
#pragma unroll
      for (int p = 0; p < 8; ++p) {
        int c = w * 8 + p;
        async_cp16(Bt + c * 64 + lane, &Bsh4[1 - cbuf][c * 64]);
      }
    }

    f32x4 acc[2][2];
#pragma unroll
    for (int si = 0; si < 2; ++si)
#pragma unroll
      for (int sj = 0; sj < 2; ++sj) acc[si][sj] = (f32x4)(0.f);

#pragma unroll
    for (int kc = 0; kc < 8; ++kc) {
      bf16x8 bv[2];
#pragma unroll
      for (int s = 0; s < 2; ++s) {
        int rb = jhalf * 32 + s * 16 + m15;
        bv[s] = ((const bf16x8*)Bsh4[cbuf])[rb * 32 + ((kc * 4 + quad) ^ (rb & 31))];
      }
      acc[0][0] = __builtin_amdgcn_mfma_f32_16x16x32_bf16(areg[0][kc], bv[0], acc[0][0], 0, 0, 0);
      acc[0][1] = __builtin_amdgcn_mfma_f32_16x16x32_bf16(areg[0][kc], bv[1], acc[0][1], 0, 0, 0);
      acc[1][0] = __builtin_amdgcn_mfma_f32_16x16x32_bf16(areg[1][kc], bv[0], acc[1][0], 0, 0, 0);
      acc[1][1] = __builtin_amdgcn_mfma_f32_16x16x32_bf16(areg[1][kc], bv[1], acc[1][1], 0, 0, 0);
    }

    // C scatter -> wave-local quadrant (32x32); swizzle key quad*2 pairs the
    // 4 stores of each acc float4 (+0/+128/+256/+384 B).
#pragma unroll
    for (int si = 0; si < 2; ++si)
#pragma unroll
      for (int sj = 0; sj < 2; ++sj) {
        int lr0 = si * 16 + quad * 4;
        int key = quad * 2;
        int lc = sj * 16 + m15;
        int gc = lc >> 2;
        int base = lr0 * 32 + ((gc ^ key) << 2) + (lc & 3);
#pragma unroll
        for (int r = 0; r < 4; ++r)
          Csw[base + r * 32] = acc[si][sj][r];
      }

    // wave-local top-8: lane scans (row trow, cols thalf*16..+15)
    {
      int cb0 = jt * 64 + jhalf * 32;
      int skey = (trow >> 1) & 6;
#pragma unroll
      for (int p = 0; p < 4; ++p) {
        int gc = thalf * 4 + p;
        float4 v = *(const float4*)&Csw[trow * 32 + ((gc ^ skey) << 2)];
        float g4 = fmaxf(fmaxf(v.x, v.y), fmaxf(v.z, v.w));
        if (g4 > thr) {
          int cbase = cb0 + gc * 4;
          float vv[4] = {v.x, v.y, v.z, v.w};
#pragma unroll
          for (int e = 0; e < 4; ++e) {
            unsigned ub = __float_as_uint(vv[e]);
            unsigned key = ((ub ^ (unsigned)(((int)ub >> 31) | 0x80000000)) & ~2047u)
                           | (unsigned)(cbase + e);
            if (key > mk[NCAND - 1]) {
              mk[NCAND - 1] = key;
#pragma unroll
              for (int q = NCAND - 1; q >= 1; --q)
                if (mk[q] > mk[q - 1]) { unsigned tm = mk[q]; mk[q] = mk[q - 1]; mk[q - 1] = tm; }
            }
          }
          unsigned kb = mk[NCAND - 1] & ~2047u;
          if (kb) {  // conservative float threshold from 8th-best key
            unsigned xm = 0x80000000u | ~(unsigned)((int)kb >> 31);
            thr = __uint_as_float(kb ^ xm);
          }
        }
      }
    }
  }

  // ---- merge 4 per-thread lists per row -> top-8 per (row, split) ----
  __syncthreads();
  unsigned* mergeK = (unsigned*)Csh;  // [64][33]
  {
    int grow = ihalf * 32 + trow;
    int q = jhalf * 2 + thalf;
#pragma unroll
    for (int k = 0; k < NCAND; ++k) mergeK[grow * 33 + q * 8 + k] = mk[k];
  }
  __syncthreads();
  if (t < 64) {
    unsigned fk[NCAND];
#pragma unroll
    for (int k = 0; k < NCAND; ++k) fk[k] = 0u;
    for (int s = 0; s < 32; ++s) {
      unsigned kk = mergeK[t * 33 + s];
      if (kk > fk[NCAND - 1]) {
        fk[NCAND - 1] = kk;
#pragma unroll
        for (int q = NCAND - 1; q >= 1; --q)
          if (fk[q] > fk[q - 1]) { unsigned tm = fk[q]; fk[q] = fk[q - 1]; fk[q - 1] = tm; }
      }
    }
#pragma unroll
    for (int k = 0; k < NCAND; ++k)
      candp[(size_t)js * (NROWS * NCAND) + (size_t)(i0 + t) * NCAND + k] =
          jbase + (int)(fk[k] & 2047u);
  }
}

// ---------------- 3. fp64 exact refine (no divides: reads stored f) ----------------
__global__ void k_refine(const float* __restrict__ f, const double* __restrict__ sqd,
                         const int* __restrict__ candp, int* __restrict__ nbr) {
  const int row = blockIdx.x * 4 + (threadIdx.x >> 6);
  const int t = threadIdx.x & 63;
  const int c = t >> 1;        // candidate 0..31
  const int seg = t & 1;       // half of D
  const int split = c >> 3, slot = c & 7;
  int j = candp[(size_t)split * (NROWS * NCAND) + (size_t)row * NCAND + slot];
  const float4* fi4 = (const float4*)(f + (size_t)row * DIM) + seg * 32;
  const float4* fj4 = (const float4*)(f + (size_t)j * DIM) + seg * 32;
  double dot = 0.0;
#pragma unroll 8
  for (int d4 = 0; d4 < 32; ++d4) {
    float4 a = fi4[d4], b = fj4[d4];
    dot = fma((double)a.x, (double)b.x, dot);
    dot = fma((double)a.y, (double)b.y, dot);
    dot = fma((double)a.z, (double)b.z, dot);
    dot = fma((double)a.w, (double)b.w, dot);
  }
  dot += __shfl_xor(dot, 1, 64);
  double key = sqd[j] - 2.0 * dot;
  bool valid = (seg == 0) && (j != row);
  for (int s = 0; s < KNN; ++s) {
    double v = valid ? key : (double)INFINITY;
    int vj = valid ? j : 0x7fffffff;
#pragma unroll
    for (int m = 1; m < 64; m <<= 1) {
      double ov = __shfl_xor(v, m, 64);
      int oj = __shfl_xor(vj, m, 64);
      if (ov < v || (ov == v && oj < vj)) { v = ov; vj = oj; }
    }
    if (valid && vj == j) valid = false;
    if (t == 0) nbr[(size_t)row * 8 + s] = vj;
  }
}

// ---------------- 4. persistent solver: Y0 + all iterations + out ----------------
// 256 blocks x 512 threads (8 waves, 4 rows/wave, lane=class). Fence-free
// agent-scope barrier, now TWO-LEVEL fan-in: 16 arrivals per group line
// (parallel across 16 lines) + 16 group-finalizers on the root line; root
// wave still reduces all 256 Eparts flat; resets by 16 lanes in parallel;
// one workgroup-release (vmcnt drain) before the gen store.
__global__ void k_solve(const float* __restrict__ scores,
                        const int* __restrict__ nbr,
                        float* __restrict__ Ya, float* __restrict__ Yb,
                        float* __restrict__ out, GS* __restrict__ gs) {
  const int b = blockIdx.x;
  const int w = threadIdx.x >> 6, lane = threadIdx.x & 63;
  const int row0 = b * 32 + w * 4;
  const int grp = (b & 15) * 32;   // group fan-in line (int index)
  __shared__ int nbl[32][5];
  __shared__ double sE[8];
  __shared__ int sflag;

  if (threadIdx.x < 160)
    nbl[threadIdx.x / 5][threadIdx.x % 5] =
        nbr[(size_t)(b * 32 + threadIdx.x / 5) * 8 + (threadIdx.x % 5)];

  float u[4], y[4];
#pragma unroll
  for (int r = 0; r < 4; ++r)
    u[r] = -logf(scores[(size_t)(row0 + r) * NCLS + lane] + 1e-10f);
#pragma unroll
  for (int r = 0; r < 4; ++r) {
    float e = expf(-u[r]);
    float sum = wave_sum64(e);
    y[r] = e / sum;
    astoref(&Ya[(size_t)(row0 + r) * NCLS + lane], y[r]);
  }
  __syncthreads();  // nbl ready

  // hoist neighbor element-offsets into registers
  int nboff[4][KNN];
#pragma unroll
  for (int r = 0; r < 4; ++r)
#pragma unroll
    for (int k = 0; k < KNN; ++k)
      nboff[r][k] = nbl[w * 4 + r][k] * NCLS + lane;

  int mygen = 1;
  // grid barrier: publish Y0 (thread 0; one-shot, serial resets fine)
  if (threadIdx.x == 0) {
    __builtin_amdgcn_fence(__ATOMIC_RELEASE, "workgroup");  // drain Y0 stores
    int old = afetchadd(&gs->gcnt[grp]);
    if (old == 15) {
      int r = afetchadd(&gs->root);
      if (r == 15) {
#pragma unroll
        for (int m = 0; m < 16; ++m) astorei(&gs->gcnt[m * 32], 0);
        astorei(&gs->root, 0);
        __builtin_amdgcn_fence(__ATOMIC_RELEASE, "workgroup");
        astorei(&gs->gen, mygen);
      }
    }
    while (aloadi(&gs->gen) < mygen) __builtin_amdgcn_s_sleep(1);
  }
  __syncthreads();
  ++mygen;

  for (int iter = 0; iter < MAXSTEPS; ++iter) {
    const float* __restrict__ Yin = (iter & 1) ? Yb : Ya;
    float* __restrict__ Yout = (iter & 1) ? Ya : Yb;
    double ew = 0.0;
#pragma unroll
    for (int r = 0; r < 4; ++r) {
      float pw = 0.f;
#pragma unroll
      for (int k = 0; k < KNN; ++k) pw += aloadf(&Yin[nboff[r][k]]);
      float e = expf(pw - u[r]);
      float sum = wave_sum64(e);
      y[r] = e / sum;
      astoref(&Yout[(size_t)(row0 + r) * NCLS + lane], y[r]);
      ew += -(double)logf(sum);
    }
    if (lane == 0) sE[w] = ew;
    __syncthreads();  // sE visible to wave 0
    if (w == 0) {
      double be = (lane < 8) ? sE[lane] : 0.0;
      be = wave_sum64d(be);
      int last = 0;
      if (lane == 0) {
        astored(&gs->Epart[b], be);
        __builtin_amdgcn_fence(__ATOMIC_RELEASE, "workgroup");  // drain Y + Epart
        int old = afetchadd(&gs->gcnt[grp]);
        if (old == 15) {
          int r = afetchadd(&gs->root);
          last = (r == 15);
        }
      }
      last = __shfl(last, 0, 64);
      if (last) {  // root wave: flat E reduction + convergence + resets + release
        double s = 0.0;
#pragma unroll
        for (int i = 0; i < 4; ++i) s += aloadd(&gs->Epart[lane + 64 * i]);
        s = wave_sum64d(s);
        if (lane < 16) astorei(&gs->gcnt[lane * 32], 0);
        if (lane == 0) {
          astorei(&gs->root, 0);
          double eo = aloadd(&gs->Eold);
          int conv = (iter > 1) && (fabs(s - eo) <= 1e-8 * fabs(eo));
          astorei(&gs->flag, conv);
          if (!conv) astored(&gs->Eold, s);
        }
        __builtin_amdgcn_fence(__ATOMIC_RELEASE, "workgroup");  // drain resets
        if (lane == 0) astorei(&gs->gen, mygen);  // release epoch
      }
      if (lane == 0) {
        while (aloadi(&gs->gen) < mygen) __builtin_amdgcn_s_sleep(1);
        sflag = aloadi(&gs->flag);
      }
    }
    __syncthreads();
    ++mygen;
    if (sflag) break;  // uniform across grid
  }

  // y regs hold the final iteration's values for this block's rows
#pragma unroll
  for (int r = 0; r < 4; ++r)
    out[(size_t)(row0 + r) * NCLS + lane] = y[r];
}

// ---------------- 0. state init ----------------
__global__ void k_init(GS* gs) {
  int t = threadIdx.x;
  if (t == 0) {
    gs->Eold = (double)INFINITY;
    gs->root = 0; gs->gen = 0; gs->flag = 0;
  }
  if (t < 16 * 32) gs->gcnt[t] = 0;
}

extern "C" void kernel_launch(void* const* d_in, const int* in_sizes, int n_in,
                              void* d_out, int out_size, void* d_ws, size_t ws_size,
                              hipStream_t stream) {
  (void)in_sizes; (void)n_in; (void)out_size; (void)ws_size;
  const float* scores = (const float*)d_in[0];
  const float* feats  = (const float*)d_in[1];
  float* out = (float*)d_out;
  char* ws = (char*)d_ws;
  // workspace layout (256B-aligned); total ~14.0 MB
  uint4*  fb    = (uint4*)(ws + 0);          //  4 MB pre-swizzled bf16 tiles
  float*  f     = (float*)(ws + 4194304);    //  8 MB fp32 normalized (dies after refine)
  float*  Ya    = (float*)(ws + 4194304);    //  2 MB (aliases f; live from k_solve)
  float*  Yb    = (float*)(ws + 6291456);    //  2 MB (aliases f)
  double* sqd   = (double*)(ws + 12582912);  // 64 KB
  int*    candp = (int*)(ws + 12648448);     //  1 MB (4 splits x 8192 x 8)
  int*    nbr   = (int*)(ws + 13697024);     // 256 KB
  GS*     gs    = (GS*)(ws + 13959168);      // ~4.6 KB

  k_init<<<1, 512, 0, stream>>>(gs);
  k_normalize<<<NROWS / 4, 256, 0, stream>>>(feats, (uint2*)fb, f, sqd);
  k_gram<<<(NROWS / 64) * NSPLIT, 256, 0, stream>>>(fb, candp);
  k_refine<<<NROWS / 4, 256, 0, stream>>>(f, sqd, candp, nbr);
  k_solve<<<PBLK, 512, 0, stream>>>(scores, nbr, Ya, Yb, out, gs);
}

// Round 12
// 246.109 us; speedup vs baseline: 2.2563x; 1.0677x over previous
//
#include <hip/hip_runtime.h>
#include <math.h>

#define NROWS 8192
#define DIM   256
#define NCLS  64
#define KNN   5
#define NCAND 8      // per (row, j-split)
#define NSPLIT 4
#define MAXSTEPS 100
#define PBLK 256     // persistent-solver blocks: 1 per CU -> co-residency guaranteed

struct GS {
  double Eold;
  double Epart[PBLK];
  int pad0[30];
  int gcnt[16 * 32];         // 16 group fan-in lines (128B apart)
  int root; int pad1[31];    // root fan-in line
  int gen;  int pad2[31];    // release line
  int flag; int pad3[31];
};

typedef __attribute__((ext_vector_type(8))) short bf16x8;
typedef __attribute__((ext_vector_type(4))) float f32x4;

typedef __attribute__((address_space(1))) unsigned int glb_u32_t;
typedef __attribute__((address_space(3))) unsigned int lds_u32_t;
// async global->LDS DMA, 16 B/lane; LDS dest = wave-uniform base + lane*16
__device__ __forceinline__ void async_cp16(const uint4* g, uint4* l) {
  __builtin_amdgcn_global_load_lds((const glb_u32_t*)(const unsigned int*)g,
                                   (lds_u32_t*)(unsigned int*)l, 16, 0, 0);
}

// agent-scope relaxed ops: coherent at L3 by construction -> no wbl2/inv fences
__device__ __forceinline__ float aloadf(const float* p) {
  return __hip_atomic_load(p, __ATOMIC_RELAXED, __HIP_MEMORY_SCOPE_AGENT);
}
__device__ __forceinline__ void astoref(float* p, float v) {
  __hip_atomic_store(p, v, __ATOMIC_RELAXED, __HIP_MEMORY_SCOPE_AGENT);
}
__device__ __forceinline__ double aloadd(const double* p) {
  return __hip_atomic_load(p, __ATOMIC_RELAXED, __HIP_MEMORY_SCOPE_AGENT);
}
__device__ __forceinline__ void astored(double* p, double v) {
  __hip_atomic_store(p, v, __ATOMIC_RELAXED, __HIP_MEMORY_SCOPE_AGENT);
}
__device__ __forceinline__ int aloadi(const int* p) {
  return __hip_atomic_load(p, __ATOMIC_RELAXED, __HIP_MEMORY_SCOPE_AGENT);
}
__device__ __forceinline__ void astorei(int* p, int v) {
  __hip_atomic_store(p, v, __ATOMIC_RELAXED, __HIP_MEMORY_SCOPE_AGENT);
}
__device__ __forceinline__ int afetchadd(int* p) {
  return __hip_atomic_fetch_add(p, 1, __ATOMIC_RELAXED, __HIP_MEMORY_SCOPE_AGENT);
}

// ---------------- wave (64-lane) reductions ----------------
__device__ __forceinline__ float wave_sum64(float v) {
#pragma unroll
  for (int m = 32; m >= 1; m >>= 1) v += __shfl_xor(v, m, 64);
  return v;
}
__device__ __forceinline__ double wave_sum64d(double v) {
#pragma unroll
  for (int m = 32; m >= 1; m >>= 1) v += __shfl_xor(v, m, 64);
  return v;
}

__device__ __forceinline__ unsigned short f2bf(float x) {  // RNE bf16
  unsigned u = __float_as_uint(x);
  u += 0x7FFFu + ((u >> 16) & 1u);
  return (unsigned short)(u >> 16);
}

// ---------------- 1. normalize: bf16 swizzled tiles + fp32 f + sqd ----------------
// fb layout (uint4 granules = 8 bf16 dims): row r -> tile T=r>>6, local row
// rl=r&63, granule g: fb_uint4[T*2048 + rl*32 + (g ^ (rl&31))].
__global__ void k_normalize(const float* __restrict__ feats, uint2* __restrict__ fb2,
                            float* __restrict__ f, double* __restrict__ sqd) {
  int row  = blockIdx.x * 4 + (threadIdx.x >> 6);
  int lane = threadIdx.x & 63;
  float4 v = ((const float4*)(feats + (size_t)row * DIM))[lane];
  double ss = (double)v.x * v.x + (double)v.y * v.y + (double)v.z * v.z + (double)v.w * v.w;
  ss = wave_sum64d(ss);
  float nr = fmaxf((float)sqrt(ss), 1e-12f);
  float4 o;  // exact fp32 division
  o.x = v.x / nr; o.y = v.y / nr; o.z = v.z / nr; o.w = v.w / nr;
  ((float4*)(f + (size_t)row * DIM))[lane] = o;
  double s2 = (double)o.x * o.x + (double)o.y * o.y + (double)o.z * o.z + (double)o.w * o.w;
  s2 = wave_sum64d(s2);
  if (lane == 0) sqd[row] = s2;
  uint2 w2;
  w2.x = (unsigned)f2bf(o.x) | ((unsigned)f2bf(o.y) << 16);
  w2.y = (unsigned)f2bf(o.z) | ((unsigned)f2bf(o.w) << 16);
  int T = row >> 6, rl = row & 63, g = lane >> 1, h = lane & 1;
  fb2[((size_t)T * 2048 + rl * 32 + (g ^ (rl & 31))) * 2 + h] = w2;
}

// ---------------- 2. MFMA bf16 candidate Gram + per-row top-8 (in-register) -------
// grid 512: (row-block ib 0..127) x (j-split js 0..3). A-fragments in regs,
// double-buffered B via async DMA -> one barrier per tile.
// OPERAND SWAP: acc = mfma(bfrag, afrag): D's col (lane&15) = A-row, D's row
// (quad*4+r) = B-col. Each lane holds 8 candidates/tile for each of its 2
// A-rows IN REGISTERS -> no C scatter / LDS scan at all. Candidate lists
// partition B-columns by (bhalf,si,quad) -> merged per-split top-8 identical
// to the scan version (same truncated keys).
#define JSPAN (NROWS / NSPLIT)  // 2048
#define GTILES (JSPAN / 64)     // 32

__launch_bounds__(256, 2)
__global__ void k_gram(const uint4* __restrict__ fb, int* __restrict__ candp) {
  __shared__ uint4 Bsh4[2][2048];   // 64 KB; buf1 stages A first
  __shared__ unsigned Ksh[4096];    // 16 KB: final merge keys [64][64] rotated

  const int t  = threadIdx.x;
  const int ib = blockIdx.x >> 2;
  const int js = blockIdx.x & 3;
  const int i0 = ib * 64;
  const int jbase = js * JSPAN;
  const int w = t >> 6, lane = t & 63;

  // DMA: A -> buf1, B tile0 -> buf0
  {
    const uint4* At = fb + (size_t)ib * 2048;
    const uint4* Bt = fb + (size_t)(js * 32) * 2048;
#pragma unroll
    for (int p = 0; p < 8; ++p) {
      int c = w * 8 + p;
      async_cp16(At + c * 64 + lane, &Bsh4[1][c * 64]);
      async_cp16(Bt + c * 64 + lane, &Bsh4[0][c * 64]);
    }
  }
  const int ahalf = w >> 1, bhalf = w & 1;
  const int m15 = lane & 15, quad = lane >> 4;

  __syncthreads();  // drain DMA: A + B0 visible

  // A-quadrant fragments -> registers (a-rows ahalf*32 + s*16 + m15)
  bf16x8 areg[2][8];
#pragma unroll
  for (int s = 0; s < 2; ++s) {
    int ra = ahalf * 32 + s * 16 + m15;
#pragma unroll
    for (int kc = 0; kc < 8; ++kc)
      areg[s][kc] = ((const bf16x8*)Bsh4[1])[ra * 32 + ((kc * 4 + quad) ^ (ra & 31))];
  }
  __syncthreads();  // buf1 reusable

  // two top-8 lists per lane: one per owned A-row (s = 0,1)
  unsigned mk[2][NCAND];
#pragma unroll
  for (int s = 0; s < 2; ++s)
#pragma unroll
    for (int k = 0; k < NCAND; ++k) mk[s][k] = 0u;
  float thr[2] = {-1e30f, -1e30f};

  for (int jt = 0; jt < GTILES; ++jt) {
    const int cbuf = jt & 1;
    if (jt > 0) __syncthreads();
    if (jt + 1 < GTILES) {
      const uint4* Bt = fb + (size_t)(js * 32 + jt + 1) * 2048;
#pragma unroll
      for (int p = 0; p < 8; ++p) {
        int c = w * 8 + p;
        async_cp16(Bt + c * 64 + lane, &Bsh4[1 - cbuf][c * 64]);
      }
    }

    f32x4 acc[2][2];  // [si = b-subtile][s = a-subtile]
#pragma unroll
    for (int si = 0; si < 2; ++si)
#pragma unroll
      for (int s = 0; s < 2; ++s) acc[si][s] = (f32x4)(0.f);

#pragma unroll
    for (int kc = 0; kc < 8; ++kc) {
      bf16x8 bv[2];
#pragma unroll
      for (int si = 0; si < 2; ++si) {
        int rb = bhalf * 32 + si * 16 + m15;
        bv[si] = ((const bf16x8*)Bsh4[cbuf])[rb * 32 + ((kc * 4 + quad) ^ (rb & 31))];
      }
      // swapped operands: D[b-col][a-row]
      acc[0][0] = __builtin_amdgcn_mfma_f32_16x16x32_bf16(bv[0], areg[0][kc], acc[0][0], 0, 0, 0);
      acc[0][1] = __builtin_amdgcn_mfma_f32_16x16x32_bf16(bv[0], areg[1][kc], acc[0][1], 0, 0, 0);
      acc[1][0] = __builtin_amdgcn_mfma_f32_16x16x32_bf16(bv[1], areg[0][kc], acc[1][0], 0, 0, 0);
      acc[1][1] = __builtin_amdgcn_mfma_f32_16x16x32_bf16(bv[1], areg[1][kc], acc[1][1], 0, 0, 0);
    }

    // in-register top-8: lane's acc[si][s][r] is (a-row = ahalf*32+s*16+m15,
    // b-col = jt*64 + bhalf*32 + si*16 + quad*4 + r)
    {
      const unsigned cbase = (unsigned)(jt * 64 + bhalf * 32 + quad * 4);
#pragma unroll
      for (int s = 0; s < 2; ++s) {
#pragma unroll
        for (int si = 0; si < 2; ++si) {
          f32x4 v = acc[si][s];
          float g4 = fmaxf(fmaxf(v[0], v[1]), fmaxf(v[2], v[3]));
          if (g4 > thr[s]) {
            unsigned cb = cbase + (unsigned)(si * 16);
#pragma unroll
            for (int e = 0; e < 4; ++e) {
              unsigned ub = __float_as_uint(v[e]);
              unsigned key = ((ub ^ (unsigned)(((int)ub >> 31) | 0x80000000)) & ~2047u)
                             | (cb + (unsigned)e);
              if (key > mk[s][NCAND - 1]) {
                mk[s][NCAND - 1] = key;
#pragma unroll
                for (int q = NCAND - 1; q >= 1; --q)
                  if (mk[s][q] > mk[s][q - 1]) {
                    unsigned tm = mk[s][q]; mk[s][q] = mk[s][q - 1]; mk[s][q - 1] = tm;
                  }
              }
            }
          }
        }
        unsigned kb = mk[s][NCAND - 1] & ~2047u;
        if (kb) {  // conservative float threshold from 8th-best key
          unsigned xm = 0x80000000u | ~(unsigned)((int)kb >> 31);
          thr[s] = __uint_as_float(kb ^ xm);
        }
      }
    }
  }

  // ---- merge 8 lists per row -> top-8 per (row, split) ----
  // Ksh[row][slot] with slot rotated by row: idx = row*64 + ((slot+row)&63)
  // -> reads by row are conflict-free without padding.
  __syncthreads();
#pragma unroll
  for (int s = 0; s < 2; ++s) {
    int row = ahalf * 32 + s * 16 + m15;
    int slot0 = bhalf * 32 + quad * 8;
#pragma unroll
    for (int k = 0; k < NCAND; ++k)
      Ksh[row * 64 + ((slot0 + k + row) & 63)] = mk[s][k];
  }
  __syncthreads();
  if (t < 64) {
    unsigned fk[NCAND];
#pragma unroll
    for (int k = 0; k < NCAND; ++k) fk[k] = 0u;
    for (int s = 0; s < 64; ++s) {
      unsigned kk = Ksh[t * 64 + ((s + t) & 63)];
      if (kk > fk[NCAND - 1]) {
        fk[NCAND - 1] = kk;
#pragma unroll
        for (int q = NCAND - 1; q >= 1; --q)
          if (fk[q] > fk[q - 1]) { unsigned tm = fk[q]; fk[q] = fk[q - 1]; fk[q - 1] = tm; }
      }
    }
#pragma unroll
    for (int k = 0; k < NCAND; ++k)
      candp[(size_t)js * (NROWS * NCAND) + (size_t)(i0 + t) * NCAND + k] =
          jbase + (int)(fk[k] & 2047u);
  }
}

// ---------------- 3. fp64 exact refine (no divides: reads stored f) ----------------
__global__ void k_refine(const float* __restrict__ f, const double* __restrict__ sqd,
                         const int* __restrict__ candp, int* __restrict__ nbr) {
  const int row = blockIdx.x * 4 + (threadIdx.x >> 6);
  const int t = threadIdx.x & 63;
  const int c = t >> 1;        // candidate 0..31
  const int seg = t & 1;       // half of D
  const int split = c >> 3, slot = c & 7;
  int j = candp[(size_t)split * (NROWS * NCAND) + (size_t)row * NCAND + slot];
  const float4* fi4 = (const float4*)(f + (size_t)row * DIM) + seg * 32;
  const float4* fj4 = (const float4*)(f + (size_t)j * DIM) + seg * 32;
  double dot = 0.0;
#pragma unroll 8
  for (int d4 = 0; d4 < 32; ++d4) {
    float4 a = fi4[d4], b = fj4[d4];
    dot = fma((double)a.x, (double)b.x, dot);
    dot = fma((double)a.y, (double)b.y, dot);
    dot = fma((double)a.z, (double)b.z, dot);
    dot = fma((double)a.w, (double)b.w, dot);
  }
  dot += __shfl_xor(dot, 1, 64);
  double key = sqd[j] - 2.0 * dot;
  bool valid = (seg == 0) && (j != row);
  for (int s = 0; s < KNN; ++s) {
    double v = valid ? key : (double)INFINITY;
    int vj = valid ? j : 0x7fffffff;
#pragma unroll
    for (int m = 1; m < 64; m <<= 1) {
      double ov = __shfl_xor(v, m, 64);
      int oj = __shfl_xor(vj, m, 64);
      if (ov < v || (ov == v && oj < vj)) { v = ov; vj = oj; }
    }
    if (valid && vj == j) valid = false;
    if (t == 0) nbr[(size_t)row * 8 + s] = vj;
  }
}

// ---------------- 4. persistent solver: Y0 + all iterations + out ----------------
// 256 blocks x 512 threads (8 waves, 4 rows/wave, lane=class). Fence-free
// agent-scope two-level barrier (R11-proven).
__global__ void k_solve(const float* __restrict__ scores,
                        const int* __restrict__ nbr,
                        float* __restrict__ Ya, float* __restrict__ Yb,
                        float* __restrict__ out, GS* __restrict__ gs) {
  const int b = blockIdx.x;
  const int w = threadIdx.x >> 6, lane = threadIdx.x & 63;
  const int row0 = b * 32 + w * 4;
  const int grp = (b & 15) * 32;   // group fan-in line (int index)
  __shared__ int nbl[32][5];
  __shared__ double sE[8];
  __shared__ int sflag;

  if (threadIdx.x < 160)
    nbl[threadIdx.x / 5][threadIdx.x % 5] =
        nbr[(size_t)(b * 32 + threadIdx.x / 5) * 8 + (threadIdx.x % 5)];

  float u[4], y[4];
#pragma unroll
  for (int r = 0; r < 4; ++r)
    u[r] = -logf(scores[(size_t)(row0 + r) * NCLS + lane] + 1e-10f);
#pragma unroll
  for (int r = 0; r < 4; ++r) {
    float e = expf(-u[r]);
    float sum = wave_sum64(e);
    y[r] = e / sum;
    astoref(&Ya[(size_t)(row0 + r) * NCLS + lane], y[r]);
  }
  __syncthreads();  // nbl ready

  // hoist neighbor element-offsets into registers
  int nboff[4][KNN];
#pragma unroll
  for (int r = 0; r < 4; ++r)
#pragma unroll
    for (int k = 0; k < KNN; ++k)
      nboff[r][k] = nbl[w * 4 + r][k] * NCLS + lane;

  int mygen = 1;
  // grid barrier: publish Y0 (thread 0; one-shot, serial resets fine)
  if (threadIdx.x == 0) {
    __builtin_amdgcn_fence(__ATOMIC_RELEASE, "workgroup");  // drain Y0 stores
    int old = afetchadd(&gs->gcnt[grp]);
    if (old == 15) {
      int r = afetchadd(&gs->root);
      if (r == 15) {
#pragma unroll
        for (int m = 0; m < 16; ++m) astorei(&gs->gcnt[m * 32], 0);
        astorei(&gs->root, 0);
        __builtin_amdgcn_fence(__ATOMIC_RELEASE, "workgroup");
        astorei(&gs->gen, mygen);
      }
    }
    while (aloadi(&gs->gen) < mygen) __builtin_amdgcn_s_sleep(1);
  }
  __syncthreads();
  ++mygen;

  for (int iter = 0; iter < MAXSTEPS; ++iter) {
    const float* __restrict__ Yin = (iter & 1) ? Yb : Ya;
    float* __restrict__ Yout = (iter & 1) ? Ya : Yb;
    double ew = 0.0;
#pragma unroll
    for (int r = 0; r < 4; ++r) {
      float pw = 0.f;
#pragma unroll
      for (int k = 0; k < KNN; ++k) pw += aloadf(&Yin[nboff[r][k]]);
      float e = expf(pw - u[r]);
      float sum = wave_sum64(e);
      y[r] = e / sum;
      astoref(&Yout[(size_t)(row0 + r) * NCLS + lane], y[r]);
      ew += -(double)logf(sum);
    }
    if (lane == 0) sE[w] = ew;
    __syncthreads();  // sE visible to wave 0
    if (w == 0) {
      double be = (lane < 8) ? sE[lane] : 0.0;
      be = wave_sum64d(be);
      int last = 0;
      if (lane == 0) {
        astored(&gs->Epart[b], be);
        __builtin_amdgcn_fence(__ATOMIC_RELEASE, "workgroup");  // drain Y + Epart
        int old = afetchadd(&gs->gcnt[grp]);
        if (old == 15) {
          int r = afetchadd(&gs->root);
          last = (r == 15);
        }
      }
      last = __shfl(last, 0, 64);
      if (last) {  // root wave: flat E reduction + convergence + resets + release
        double s = 0.0;
#pragma unroll
        for (int i = 0; i < 4; ++i) s += aloadd(&gs->Epart[lane + 64 * i]);
        s = wave_sum64d(s);
        if (lane < 16) astorei(&gs->gcnt[lane * 32], 0);
        if (lane == 0) {
          astorei(&gs->root, 0);
          double eo = aloadd(&gs->Eold);
          int conv = (iter > 1) && (fabs(s - eo) <= 1e-8 * fabs(eo));
          astorei(&gs->flag, conv);
          if (!conv) astored(&gs->Eold, s);
        }
        __builtin_amdgcn_fence(__ATOMIC_RELEASE, "workgroup");  // drain resets
        if (lane == 0) astorei(&gs->gen, mygen);  // release epoch
      }
      if (lane == 0) {
        while (aloadi(&gs->gen) < mygen) __builtin_amdgcn_s_sleep(1);
        sflag = aloadi(&gs->flag);
      }
    }
    __syncthreads();
    ++mygen;
    if (sflag) break;  // uniform across grid
  }

  // y regs hold the final iteration's values for this block's rows
#pragma unroll
  for (int r = 0; r < 4; ++r)
    out[(size_t)(row0 + r) * NCLS + lane] = y[r];
}

// ---------------- 0. state init ----------------
__global__ void k_init(GS* gs) {
  int t = threadIdx.x;
  if (t == 0) {
    gs->Eold = (double)INFINITY;
    gs->root = 0; gs->gen = 0; gs->flag = 0;
  }
  if (t < 16 * 32) gs->gcnt[t] = 0;
}

extern "C" void kernel_launch(void* const* d_in, const int* in_sizes, int n_in,
                              void* d_out, int out_size, void* d_ws, size_t ws_size,
                              hipStream_t stream) {
  (void)in_sizes; (void)n_in; (void)out_size; (void)ws_size;
  const float* scores = (const float*)d_in[0];
  const float* feats  = (const float*)d_in[1];
  float* out = (float*)d_out;
  char* ws = (char*)d_ws;
  // workspace layout (256B-aligned); total ~14.0 MB
  uint4*  fb    = (uint4*)(ws + 0);          //  4 MB pre-swizzled bf16 tiles
  float*  f     = (float*)(ws + 4194304);    //  8 MB fp32 normalized (dies after refine)
  float*  Ya    = (float*)(ws + 4194304);    //  2 MB (aliases f; live from k_solve)
  float*  Yb    = (float*)(ws + 6291456);    //  2 MB (aliases f)
  double* sqd   = (double*)(ws + 12582912);  // 64 KB
  int*    candp = (int*)(ws + 12648448);     //  1 MB (4 splits x 8192 x 8)
  int*    nbr   = (int*)(ws + 13697024);     // 256 KB
  GS*     gs    = (GS*)(ws + 13959168);      // ~4.6 KB

  k_init<<<1, 512, 0, stream>>>(gs);
  k_normalize<<<NROWS / 4, 256, 0, stream>>>(feats, (uint2*)fb, f, sqd);
  k_gram<<<(NROWS / 64) * NSPLIT, 256, 0, stream>>>(fb, candp);
  k_refine<<<NROWS / 4, 256, 0, stream>>>(f, sqd, candp, nbr);
  k_solve<<<PBLK, 512, 0, stream>>>(scores, nbr, Ya, Yb, out, gs);
}